// Round 3
// baseline (429.937 us; speedup 1.0000x reference)
//
#include <hip/hip_runtime.h>

// PretrainedCNN: normalized-convolution U-Net, B=16, 512x640, NC=2.
// Inputs fp32; OUTPUT d_out fp32: xout plane (n0) then cout plane (n0).
// Intermediates fp32 planar [ch][b][h][w], plane stride NB*npix.
// Round 11: enc_full + navg3f were latency-bound (VALUBusy 47%, VGPR=44:
// compiler allocated for the 8-wave/EU bin though LDS caps at 5 blocks/CU,
// so no room to prefetch LDS rows -> read/wait/fma serial). Fix: 
// amdgpu_waves_per_eu(4,4) to unlock the 128-VGPR bin (4 blocks/CU) +
// explicit double-buffered row prefetch in the conv inner loops (load row
// r+1 while FMA'ing row r; per-channel accumulation order unchanged).
// navg5v keeps the compact conv (its LDS cap is 7 blocks/CU; >64 VGPR
// would cost real occupancy there).

#define NB 16

typedef __attribute__((ext_vector_type(2))) float f32x2;

__device__ __forceinline__ f32x2 splat2(float s) { f32x2 v = {s, s}; return v; }
__device__ __forceinline__ float frcp(float x) { return __builtin_amdgcn_rcpf(x); }

constexpr int TX = 32, TY = 8;

// ================= fused full-res encoder =================
// output tile 32x16; stage 44x28 (halo 6); L1 40x24 (halo 4); L2 36x20 (halo 2)
constexpr int FTW = 32, FTH = 16;
constexpr int FSW = 44, FSH = 28;
constexpr int FAW = 40, FAH = 24;
constexpr int FAS = 44;   // padded s1 stride: 11 float4-groups (odd) -> conflict-free diagonal
constexpr int FBW = 36, FBH = 20;

// compact conv (low VGPR profile) -- used where occupancy is LDS-rich
template<int CIN>
__device__ __forceinline__ void conv5x4(const float* sc, const float* sp,
                                        int chStride, int rw,
                                        const float* __restrict__ w,
                                        f32x2 ca[4], f32x2 pa[4]) {
#pragma unroll
    for (int j = 0; j < 4; ++j) { ca[j] = splat2(0.f); pa[j] = splat2(0.f); }
#pragma unroll
    for (int ci = 0; ci < CIN; ++ci) {
#pragma unroll
        for (int kh = 0; kh < 5; ++kh) {
            const float* rc = sc + ci * chStride + kh * rw;
            const float* rp = sp + ci * chStride + kh * rw;
            float cw[8], pw[8];
            *(float4*)&cw[0] = *(const float4*)rc;
            *(float4*)&cw[4] = *(const float4*)(rc + 4);
            *(float4*)&pw[0] = *(const float4*)rp;
            *(float4*)&pw[4] = *(const float4*)(rp + 4);
#pragma unroll
            for (int kw = 0; kw < 5; ++kw) {
                const int q = (ci * 5 + kh) * 5 + kw;
                const f32x2 wv = { w[q], w[CIN * 25 + q] };
#pragma unroll
                for (int j = 0; j < 4; ++j) {
                    ca[j] += splat2(cw[j + kw]) * wv;   // v_pk_fma_f32
                    pa[j] += splat2(pw[j + kw]) * wv;
                }
            }
        }
    }
}

// pipelined conv (double-buffered rows, higher VGPR) -- used where LDS
// already caps blocks/CU at 4 so the registers are free.
template<int CIN>
__device__ __forceinline__ void conv5x4p(const float* sc, const float* sp,
                                         int chStride, int rw,
                                         const float* __restrict__ w,
                                         f32x2 ca[4], f32x2 pa[4]) {
    constexpr int R = CIN * 5;
    float cw[2][8], pw[2][8];
    auto ld = [&](int r, int s) {
        const int ci = r / 5, kh = r - ci * 5;
        const float* rc = sc + ci * chStride + kh * rw;
        const float* rp = sp + ci * chStride + kh * rw;
        *(float4*)&cw[s][0] = *(const float4*)rc;
        *(float4*)&cw[s][4] = *(const float4*)(rc + 4);
        *(float4*)&pw[s][0] = *(const float4*)rp;
        *(float4*)&pw[s][4] = *(const float4*)(rp + 4);
    };
#pragma unroll
    for (int j = 0; j < 4; ++j) { ca[j] = splat2(0.f); pa[j] = splat2(0.f); }
    ld(0, 0);
#pragma unroll
    for (int r = 0; r < R; ++r) {
        const int s = r & 1;
        if (r + 1 < R) ld(r + 1, (r + 1) & 1);      // prefetch next row
        const int ci = r / 5, kh = r - ci * 5;
#pragma unroll
        for (int kw = 0; kw < 5; ++kw) {
            const int q = (ci * 5 + kh) * 5 + kw;
            const f32x2 wv = { w[q], w[CIN * 25 + q] };
#pragma unroll
            for (int j = 0; j < 4; ++j) {
                ca[j] += splat2(cw[s][j + kw]) * wv;
                pa[j] += splat2(pw[s][j + kw]) * wv;
            }
        }
    }
}

template<int CIN>
__device__ __forceinline__ void conv3x4p(const float* sc, const float* sp,
                                         int chStride, int rw,
                                         const float* __restrict__ w,
                                         f32x2 ca[4], f32x2 pa[4]) {
    constexpr int R = CIN * 3;
    float cw[2][6], pw[2][6];
    auto ld = [&](int r, int s) {
        const int ci = r / 3, kh = r - ci * 3;
        const float* rc = sc + ci * chStride + kh * rw;
        const float* rp = sp + ci * chStride + kh * rw;
        *(float4*)&cw[s][0] = *(const float4*)rc;
        *(float2*)&cw[s][4] = *(const float2*)(rc + 4);
        *(float4*)&pw[s][0] = *(const float4*)rp;
        *(float2*)&pw[s][4] = *(const float2*)(rp + 4);
    };
#pragma unroll
    for (int j = 0; j < 4; ++j) { ca[j] = splat2(0.f); pa[j] = splat2(0.f); }
    ld(0, 0);
#pragma unroll
    for (int r = 0; r < R; ++r) {
        const int s = r & 1;
        if (r + 1 < R) ld(r + 1, (r + 1) & 1);
        const int ci = r / 3, kh = r - ci * 3;
#pragma unroll
        for (int kw = 0; kw < 3; ++kw) {
            const int q = (ci * 3 + kh) * 3 + kw;
            const f32x2 wv = { w[q], w[CIN * 9 + q] };
#pragma unroll
            for (int j = 0; j < 4; ++j) {
                ca[j] += splat2(cw[s][j + kw]) * wv;
                pa[j] += splat2(pw[s][j + kw]) * wv;
            }
        }
    }
}

// s0 (input stage) and s2 (L2 output) never live simultaneously: overlay.
union EncSmem {
    struct { float c[FSH][FSW]; float p[FSH][FSW]; } s0;                 // 9856 B
    struct { float c[2][FBH][FBW]; float p[2][FBH][FBW]; } s2;           // 11520 B
};

__global__ __launch_bounds__(256)
__attribute__((amdgpu_waves_per_eu(4, 4)))
void enc_full_kernel(const float* __restrict__ x0, const float* __restrict__ c0,
                     const float* __restrict__ w1, const float* __restrict__ b1,
                     const float* __restrict__ w2, const float* __restrict__ b2,
                     const float* __restrict__ w3, const float* __restrict__ b3,
                     float* __restrict__ FAx, float* __restrict__ FAc,
                     float* __restrict__ HPx, float* __restrict__ HPc,
                     int H, int W) {
    __shared__ __align__(16) EncSmem u;
    __shared__ __align__(16) float s1c[2][FAH][FAS], s1p[2][FAH][FAS];
    __shared__ float sinvf[6], sbf[6];   // per-layer {o0,o1}: [L1,L1,L2,L2,L3,L3]

    const int tid = threadIdx.x;
    const int b = blockIdx.z;
    const int Y0 = blockIdx.y * FTH, X0 = blockIdx.x * FTW;
    const int npix = H * W;
    const size_t bofs = (size_t)b * npix;
    const size_t chs = (size_t)NB * npix;

    // block-uniform: stage window fully inside the image?
    const bool interior = (X0 >= 6) && (X0 + FTW + 6 <= W) && (Y0 >= 6) && (Y0 + FTH + 6 <= H);

    // 6 threads compute the weight-sum reciprocals + biases; LDS broadcast.
    if (tid < 6) {
        const int L = tid >> 1, o = tid & 1;
        const float* wl = (L == 0) ? w1 : (L == 1) ? w2 : w3;
        const float* bl = (L == 0) ? b1 : (L == 1) ? b2 : b3;
        const int n = (L == 0) ? 25 : 50;
        float s = 0.f;
        for (int i = 0; i < n; ++i) s += wl[o * n + i];
        sinvf[tid] = 1.f / s;
        sbf[tid] = bl[o];
    }

    // stage input tile
    if (interior) {
        const size_t o0 = bofs + (size_t)(Y0 - 6) * W + (X0 - 6);
        for (int i = tid; i < FSH * FSW; i += 256) {
            const int ly = i / FSW, lx = i - ly * FSW;
            const size_t o = o0 + (size_t)ly * W + lx;
            const float cv = c0[o];
            u.s0.c[ly][lx] = cv; u.s0.p[ly][lx] = x0[o] * cv;
        }
    } else {
        for (int i = tid; i < FSH * FSW; i += 256) {
            const int ly = i / FSW, lx = i - ly * FSW;
            const int gy = Y0 + ly - 6, gx = X0 + lx - 6;
            float cv = 0.f, pv = 0.f;
            if (gy >= 0 && gy < H && gx >= 0 && gx < W) {
                const size_t o = bofs + (size_t)gy * W + gx;
                cv = c0[o]; pv = x0[o] * cv;
            }
            u.s0.c[ly][lx] = cv; u.s0.p[ly][lx] = pv;
        }
    }
    __syncthreads();

    // ---- L1: 40x24, CIN=1 -> s1 (float4 stores) ----
    if (tid < FAH * (FAW / 4)) {
        const int row = tid / (FAW / 4), lx = (tid % (FAW / 4)) * 4;
        f32x2 ca[4], pa[4];
        conv5x4p<1>(&u.s0.c[row][lx], &u.s0.p[row][lx], 0, FSW, w1, ca, pa);
        const f32x2 iv = { sinvf[0], sinvf[1] };
        const f32x2 bb = { sbf[0], sbf[1] };
        float cq[2][4], pq[2][4];
        if (interior) {
#pragma unroll
            for (int j = 0; j < 4; ++j) {
                f32x2 r = { frcp(ca[j].x + 1e-20f), frcp(ca[j].y + 1e-20f) };
                const f32x2 xv = pa[j] * r + bb;
                const f32x2 cvv = ca[j] * iv;
                cq[0][j] = cvv.x;            cq[1][j] = cvv.y;
                pq[0][j] = xv.x * cvv.x;     pq[1][j] = xv.y * cvv.y;
            }
        } else {
            const int gy = Y0 + row - 4;
#pragma unroll
            for (int j = 0; j < 4; ++j) {
                const int gx = X0 + lx + j - 4;
                const bool in = (gy >= 0 && gy < H && gx >= 0 && gx < W);
                f32x2 r = { frcp(ca[j].x + 1e-20f), frcp(ca[j].y + 1e-20f) };
                const f32x2 xv = pa[j] * r + bb;
                const f32x2 cvv = ca[j] * iv;
                cq[0][j] = in ? cvv.x : 0.f;            cq[1][j] = in ? cvv.y : 0.f;
                pq[0][j] = in ? xv.x * cvv.x : 0.f;     pq[1][j] = in ? xv.y * cvv.y : 0.f;
            }
        }
#pragma unroll
        for (int o = 0; o < 2; ++o) {
            *(float4*)&s1c[o][row][lx] = make_float4(cq[o][0], cq[o][1], cq[o][2], cq[o][3]);
            *(float4*)&s1p[o][row][lx] = make_float4(pq[o][0], pq[o][1], pq[o][2], pq[o][3]);
        }
    }
    __syncthreads();   // also: s0 reads complete -> s2 may overwrite the union

    // ---- L2: 36x20, CIN=2 -> s2 (float4 stores, overlays s0) ----
    if (tid < FBH * (FBW / 4)) {
        const int row = tid / (FBW / 4), lx = (tid % (FBW / 4)) * 4;
        f32x2 ca[4], pa[4];
        conv5x4p<2>(&s1c[0][row][lx], &s1p[0][row][lx], FAH * FAS, FAS, w2, ca, pa);
        const f32x2 iv = { sinvf[2], sinvf[3] };
        const f32x2 bb = { sbf[2], sbf[3] };
        float cq[2][4], pq[2][4];
        if (interior) {
#pragma unroll
            for (int j = 0; j < 4; ++j) {
                f32x2 r = { frcp(ca[j].x + 1e-20f), frcp(ca[j].y + 1e-20f) };
                const f32x2 xv = pa[j] * r + bb;
                const f32x2 cvv = ca[j] * iv;
                cq[0][j] = cvv.x;            cq[1][j] = cvv.y;
                pq[0][j] = xv.x * cvv.x;     pq[1][j] = xv.y * cvv.y;
            }
        } else {
            const int gy = Y0 + row - 2;
#pragma unroll
            for (int j = 0; j < 4; ++j) {
                const int gx = X0 + lx + j - 2;
                const bool in = (gy >= 0 && gy < H && gx >= 0 && gx < W);
                f32x2 r = { frcp(ca[j].x + 1e-20f), frcp(ca[j].y + 1e-20f) };
                const f32x2 xv = pa[j] * r + bb;
                const f32x2 cvv = ca[j] * iv;
                cq[0][j] = in ? cvv.x : 0.f;            cq[1][j] = in ? cvv.y : 0.f;
                pq[0][j] = in ? xv.x * cvv.x : 0.f;     pq[1][j] = in ? xv.y * cvv.y : 0.f;
            }
        }
#pragma unroll
        for (int o = 0; o < 2; ++o) {
            *(float4*)&u.s2.c[o][row][lx] = make_float4(cq[o][0], cq[o][1], cq[o][2], cq[o][3]);
            *(float4*)&u.s2.p[o][row][lx] = make_float4(pq[o][0], pq[o][1], pq[o][2], pq[o][3]);
        }
    }
    __syncthreads();

    // ---- L3: 32x16, CIN=2 -> global FA + pooled HP ----
    if (tid < FTH * (FTW / 4)) {
        const int row = tid / (FTW / 4), lx = (tid % (FTW / 4)) * 4;
        f32x2 ca[4], pa[4];
        conv5x4p<2>(&u.s2.c[0][row][lx], &u.s2.p[0][row][lx], FBH * FBW, FBW, w3, ca, pa);
        const f32x2 iv = { sinvf[4], sinvf[5] };
        const f32x2 bb = { sbf[4], sbf[5] };
        float xv[2][4], cv[2][4];
#pragma unroll
        for (int j = 0; j < 4; ++j) {
            f32x2 r = { frcp(ca[j].x + 1e-20f), frcp(ca[j].y + 1e-20f) };
            const f32x2 x2 = pa[j] * r + bb;
            const f32x2 c2 = ca[j] * iv;
            xv[0][j] = x2.x; xv[1][j] = x2.y;
            cv[0][j] = c2.x; cv[1][j] = c2.y;
        }
        const int gy = Y0 + row;
        const size_t base = bofs + (size_t)gy * W + (X0 + lx);
#pragma unroll
        for (int o = 0; o < 2; ++o) {
            *(float4*)(FAx + o * chs + base) = make_float4(xv[o][0], xv[o][1], xv[o][2], xv[o][3]);
            *(float4*)(FAc + o * chs + base) = make_float4(cv[o][0], cv[o][1], cv[o][2], cv[o][3]);
        }
        // pool 2x2 (first-wins argmax of c): partner row via shfl_xor(8)
        float pcv[2][4], pxv[2][4];
#pragma unroll
        for (int o = 0; o < 2; ++o)
#pragma unroll
            for (int j = 0; j < 4; ++j) {
                pcv[o][j] = __shfl_xor(cv[o][j], 8);
                pxv[o][j] = __shfl_xor(xv[o][j], 8);
            }
        if ((row & 1) == 0) {
            const int Wh = W >> 1;
            const int np1 = (H >> 1) * Wh;
            const int hy = (Y0 + row) >> 1;
            const int hx0 = (X0 + lx) >> 1;
#pragma unroll
            for (int o = 0; o < 2; ++o)
#pragma unroll
                for (int g = 0; g < 2; ++g) {
                    const float c00 = cv[o][2 * g], c01 = cv[o][2 * g + 1];
                    const float c10 = pcv[o][2 * g], c11 = pcv[o][2 * g + 1];
                    const float x00 = xv[o][2 * g], x01 = xv[o][2 * g + 1];
                    const float x10 = pxv[o][2 * g], x11 = pxv[o][2 * g + 1];
                    float bc = c00, bx = x00;
                    if (c01 > bc) { bc = c01; bx = x01; }
                    if (c10 > bc) { bc = c10; bx = x10; }
                    if (c11 > bc) { bc = c11; bx = x11; }
                    const size_t ho = (size_t)o * NB * np1 + (size_t)b * np1 + (size_t)hy * Wh + hx0 + g;
                    HPc[ho] = bc * 0.25f;
                    HPx[ho] = bx;
                }
        }
    }
}

// ================= vectorized sub-res 5x5 (4 px/thread) =================
// tile 64x16, stage 68x20 (halo 2), stride 68 floats = 17 groups (odd) -> latin
constexpr int VTW = 64, VTH = 16, VSW = 68, VSH = 20;

__global__ __launch_bounds__(256)
void navg5v_kernel(const float* __restrict__ xin, const float* __restrict__ cin,
                   const float* __restrict__ w, const float* __restrict__ bias,
                   float* __restrict__ xout, float* __restrict__ cout,
                   int H, int W) {
    __shared__ __align__(16) float sc[2][VSH][VSW], sp[2][VSH][VSW];   // 21760 B
    __shared__ float sinvf[2];

    const int tid = threadIdx.x;
    const int b = blockIdx.z;
    const int Y0 = blockIdx.y * VTH, X0 = blockIdx.x * VTW;
    const int npix = H * W;
    const size_t bofs = (size_t)b * npix;
    const size_t chs = (size_t)NB * npix;

    if (tid < 2) {
        float s = 0.f;
        for (int i = 0; i < 50; ++i) s += w[tid * 50 + i];
        sinvf[tid] = 1.f / s;
    }

    for (int ci = 0; ci < 2; ++ci) {
        const size_t base = (size_t)ci * chs + bofs;
        for (int i = tid; i < VSH * VSW; i += 256) {
            const int ly = i / VSW, lx = i - ly * VSW;
            const int gy = Y0 + ly - 2, gx = X0 + lx - 2;
            float cv = 0.f, pv = 0.f;
            if (gy >= 0 && gy < H && gx >= 0 && gx < W) {
                const size_t o = base + (size_t)gy * W + gx;
                cv = cin[o]; pv = xin[o] * cv;
            }
            sc[ci][ly][lx] = cv; sp[ci][ly][lx] = pv;
        }
    }
    __syncthreads();

    const int row = tid >> 4, lx4 = (tid & 15) * 4;
    f32x2 ca[4], pa[4];
    conv5x4<2>(&sc[0][row][lx4], &sp[0][row][lx4], VSH * VSW, VSW, w, ca, pa);

    const int gy = Y0 + row, gx = X0 + lx4;
    if (gy < H && gx < W) {
        const float bb0 = bias[0], bb1 = bias[1];
        float xq[2][4], cq[2][4];
#pragma unroll
        for (int j = 0; j < 4; ++j) {
            f32x2 r = { frcp(ca[j].x + 1e-20f), frcp(ca[j].y + 1e-20f) };
            xq[0][j] = pa[j].x * r.x + bb0;  xq[1][j] = pa[j].y * r.y + bb1;
            cq[0][j] = ca[j].x * sinvf[0];   cq[1][j] = ca[j].y * sinvf[1];
        }
        const size_t off = bofs + (size_t)gy * W + gx;
#pragma unroll
        for (int o = 0; o < 2; ++o) {
            *(float4*)(xout + o * chs + off) = make_float4(xq[o][0], xq[o][1], xq[o][2], xq[o][3]);
            *(float4*)(cout + o * chs + off) = make_float4(cq[o][0], cq[o][1], cq[o][2], cq[o][3]);
        }
    }
}

__global__ void pool_kernel(const float* __restrict__ xin, const float* __restrict__ cin,
                            float* __restrict__ xout, float* __restrict__ cout,
                            int Hh, int Wh) {
    const int nplane = Hh * Wh;
    const int total = 2 * NB * nplane;
    const int idx = blockIdx.x * blockDim.x + threadIdx.x;
    if (idx >= total) return;
    const int p = idx / nplane;
    const int q = idx - p * nplane;
    const int h = q / Wh, wc = q - h * Wh;
    const int Wf = 2 * Wh;
    const size_t ibase = (size_t)p * 4 * nplane + (size_t)(2 * h) * Wf + 2 * wc;
    const float c00 = cin[ibase], c01 = cin[ibase + 1];
    const float c10 = cin[ibase + Wf], c11 = cin[ibase + Wf + 1];
    float best = c00; size_t boff = ibase;
    if (c01 > best) { best = c01; boff = ibase + 1; }
    if (c10 > best) { best = c10; boff = ibase + Wf; }
    if (c11 > best) { best = c11; boff = ibase + Wf + 1; }
    cout[idx] = best * 0.25f;
    xout[idx] = xin[boff];
}

// ================= sub-res 3x3 cat kernels (1 px/thread, cheap layers) ======
template<bool UPA, bool UPB>
__global__ __launch_bounds__(256)
void navg3_kernel(const float* __restrict__ xA, const float* __restrict__ cA,
                  const float* __restrict__ xB, const float* __restrict__ cB,
                  const float* __restrict__ w, const float* __restrict__ bias,
                  float* __restrict__ xout, float* __restrict__ cout,
                  int H, int W) {
    __shared__ float sc[4][TY + 2][TX + 2];
    __shared__ float sp[4][TY + 2][TX + 2];
    __shared__ float sinvf[2];

    const int b = blockIdx.z;
    const int npix = H * W;
    const size_t chs = (size_t)NB * npix;
    const int tid = threadIdx.y * TX + threadIdx.x;

    if (tid < 2) {
        float s = 0.f;
        for (int i = 0; i < 36; ++i) s += w[tid * 36 + i];
        sinvf[tid] = 1.f / s;
    }

    const int y0 = blockIdx.y * TY - 1;
    const int x0 = blockIdx.x * TX - 1;
    const int Ws2 = W >> 1;
    const int npixS = (H >> 1) * Ws2;

#pragma unroll
    for (int ch = 0; ch < 4; ++ch) {
        const bool up = (ch < 2) ? UPA : UPB;
        const float* xs = (ch < 2) ? xA : xB;
        const float* cs = (ch < 2) ? cA : cB;
        const int sch = ch & 1;
        const size_t base = up ? ((size_t)sch * NB * npixS + (size_t)b * npixS)
                               : ((size_t)sch * chs + (size_t)b * npix);
        for (int i = tid; i < (TY + 2) * (TX + 2); i += 256) {
            const int ly = i / (TX + 2), lx = i % (TX + 2);
            const int gy = y0 + ly, gx = x0 + lx;
            float cv = 0.f, pv = 0.f;
            if (gy >= 0 && gy < H && gx >= 0 && gx < W) {
                const size_t o = up ? (base + (size_t)(gy >> 1) * Ws2 + (gx >> 1))
                                    : (base + (size_t)gy * W + gx);
                cv = cs[o];
                pv = xs[o] * cv;
            }
            sc[ch][ly][lx] = cv;
            sp[ch][ly][lx] = pv;
        }
    }
    __syncthreads();

    const int gh = blockIdx.y * TY + threadIdx.y;
    const int gw = blockIdx.x * TX + threadIdx.x;
    if (gh < H && gw < W) {
        const size_t off = (size_t)b * npix + (size_t)gh * W + gw;
        f32x2 ca = splat2(0.f), pa = splat2(0.f);
#pragma unroll
        for (int ci = 0; ci < 4; ++ci)
#pragma unroll
            for (int kh = 0; kh < 3; ++kh)
#pragma unroll
                for (int kw = 0; kw < 3; ++kw) {
                    const int q = (ci * 3 + kh) * 3 + kw;
                    const f32x2 wv = { w[q], w[36 + q] };
                    ca += splat2(sc[ci][threadIdx.y + kh][threadIdx.x + kw]) * wv;
                    pa += splat2(sp[ci][threadIdx.y + kh][threadIdx.x + kw]) * wv;
                }
        xout[off]       = pa.x * frcp(ca.x + 1e-20f) + bias[0];
        xout[chs + off] = pa.y * frcp(ca.y + 1e-20f) + bias[1];
        cout[off]       = ca.x * sinvf[0];
        cout[chs + off] = ca.y * sinvf[1];
    }
}

// ================= final fused layer: cat(up2(HA), FA) -> 3x3 -> 1x1 =======
// tile 32x32 (4 px/thread), stage 34x34 @ stride 36 (9 groups, latin)
constexpr int GTW = 32, GTH = 32, GSW = 34, GSH = 34, GSS = 36;

__global__ __launch_bounds__(256)
__attribute__((amdgpu_waves_per_eu(4, 4)))
void navg3f_kernel(const float* __restrict__ xA, const float* __restrict__ cA,   // half-res (up2)
                   const float* __restrict__ xB, const float* __restrict__ cB,   // full-res
                   const float* __restrict__ w, const float* __restrict__ bias,
                   const float* __restrict__ w4, const float* __restrict__ b4,
                   float* __restrict__ xout, float* __restrict__ cout,
                   int H, int W) {
    __shared__ __align__(16) float sc[4][GSH][GSS], sp[4][GSH][GSS];   // 39168 B
    __shared__ float sinvf[2];

    const int tid = threadIdx.x;
    const int b = blockIdx.z;
    const int Y0 = blockIdx.y * GTH, X0 = blockIdx.x * GTW;
    const int npix = H * W;
    const size_t bofs = (size_t)b * npix;
    const size_t chs = (size_t)NB * npix;
    const int Ws2 = W >> 1;
    const int npixS = (H >> 1) * Ws2;

    if (tid < 2) {
        float s = 0.f;
        for (int i = 0; i < 36; ++i) s += w[tid * 36 + i];
        sinvf[tid] = 1.f / s;
    }

#pragma unroll
    for (int ch = 0; ch < 4; ++ch) {
        const bool up = (ch < 2);
        const float* xs = up ? xA : xB;
        const float* cs = up ? cA : cB;
        const int sch = ch & 1;
        const size_t base = up ? ((size_t)sch * NB * npixS + (size_t)b * npixS)
                               : ((size_t)sch * chs + bofs);
        for (int i = tid; i < GSH * GSW; i += 256) {
            const int ly = i / GSW, lx = i - ly * GSW;
            const int gy = Y0 + ly - 1, gx = X0 + lx - 1;
            float cv = 0.f, pv = 0.f;
            if (gy >= 0 && gy < H && gx >= 0 && gx < W) {
                const size_t o = up ? (base + (size_t)(gy >> 1) * Ws2 + (gx >> 1))
                                    : (base + (size_t)gy * W + gx);
                cv = cs[o]; pv = xs[o] * cv;
            }
            sc[ch][ly][lx] = cv; sp[ch][ly][lx] = pv;
        }
    }
    __syncthreads();

    const int row = tid >> 3, lx4 = (tid & 7) * 4;
    f32x2 ca[4], pa[4];
    conv3x4p<4>(&sc[0][row][lx4], &sp[0][row][lx4], GSH * GSS, GSS, w, ca, pa);

    const float w40 = w4[0], w41 = w4[1], b40 = b4[0];
    const float inv4 = frcp(w40 + w41);
    const float bb0 = bias[0], bb1 = bias[1];
    float xq[4], cq[4];
#pragma unroll
    for (int j = 0; j < 4; ++j) {
        const float xv0 = pa[j].x * frcp(ca[j].x + 1e-20f) + bb0;
        const float xv1 = pa[j].y * frcp(ca[j].y + 1e-20f) + bb1;
        const float cv0 = ca[j].x * sinvf[0];
        const float cv1 = ca[j].y * sinvf[1];
        const float ca4 = w40 * cv0 + w41 * cv1;
        xq[j] = (w40 * xv0 * cv0 + w41 * xv1 * cv1) * frcp(ca4 + 1e-20f) + b40;
        cq[j] = ca4 * inv4;
    }
    const size_t off = bofs + (size_t)(Y0 + row) * W + (X0 + lx4);
    *(float4*)(xout + off) = make_float4(xq[0], xq[1], xq[2], xq[3]);
    *(float4*)(cout + off) = make_float4(cq[0], cq[1], cq[2], cq[3]);
}

extern "C" void kernel_launch(void* const* d_in, const int* in_sizes, int n_in,
                              void* d_out, int out_size, void* d_ws, size_t ws_size,
                              hipStream_t stream) {
    const float* x0  = (const float*)d_in[0];
    const float* c0  = (const float*)d_in[1];
    const float* w1  = (const float*)d_in[2];
    const float* w2  = (const float*)d_in[3];
    const float* w3  = (const float*)d_in[4];
    const float* w4  = (const float*)d_in[5];
    const float* w34 = (const float*)d_in[6];
    const float* w23 = (const float*)d_in[7];
    const float* w12 = (const float*)d_in[8];
    const float* b1  = (const float*)d_in[9];
    const float* b2  = (const float*)d_in[10];
    const float* b3  = (const float*)d_in[11];
    const float* b4  = (const float*)d_in[12];
    const float* b34 = (const float*)d_in[13];
    const float* b23 = (const float*)d_in[14];
    const float* b12 = (const float*)d_in[15];

    float* out = (float*)d_out;   // fp32: xout plane then cout plane

    const int H0 = 512, W0 = 640, H1 = 256, W1 = 320, H2 = 128, W2 = 160, H3 = 64, W3 = 80;
    const size_t n0 = (size_t)NB * H0 * W0;
    const size_t n1 = n0 / 4, n2 = n0 / 16, n3 = n0 / 64;

    float* ws = (float*)d_ws;
    float* FAx = ws;            // x1 (2ch) -- persists to the end
    float* FAc = ws + 2 * n0;   // c1 (2ch)
    float* sub = ws + 4 * n0;   // sub-res arena
    float* HPx = sub;               sub += 2 * n1;
    float* HPc = sub;               sub += 2 * n1;
    float* HAx = sub;               sub += 2 * n1;
    float* HAc = sub;               sub += 2 * n1;
    float* QPx = sub;               sub += 2 * n2;
    float* QPc = sub;               sub += 2 * n2;
    float* QAx = sub;               sub += 2 * n2;
    float* QAc = sub;               sub += 2 * n2;
    float* EPx = sub;               sub += 2 * n3;
    float* EPc = sub;               sub += 2 * n3;
    float* EAx = sub;               sub += 2 * n3;
    float* EAc = sub;               sub += 2 * n3;

    dim3 blk(TX, TY);
    auto gdim  = [](int W, int H) { return dim3((W + TX - 1) / TX, (H + TY - 1) / TY, NB); };
    auto gdim5 = [](int W, int H) { return dim3((W + VTW - 1) / VTW, (H + VTH - 1) / VTH, NB); };

    // L1+L2+L3+pool fused: x0,c0 -> FA (x1,c1 full res) + HP (pooled half res)
    enc_full_kernel<<<dim3(W0 / FTW, H0 / FTH, NB), 256, 0, stream>>>(
        x0, c0, w1, b1, w2, b2, w3, b3, FAx, FAc, HPx, HPc, H0, W0);

    // L5: HP -> HA (w2,b2)
    navg5v_kernel<<<gdim5(W1, H1), 256, 0, stream>>>(HPx, HPc, w2, b2, HAx, HAc, H1, W1);
    // L6: HA -> HP (w3,b3)   [HP := x2_ds,c2_ds]
    navg5v_kernel<<<gdim5(W1, H1), 256, 0, stream>>>(HAx, HAc, w3, b3, HPx, HPc, H1, W1);
    // pool -> quarter
    pool_kernel<<<(int)((2 * n2 + 255) / 256), 256, 0, stream>>>(HPx, HPc, QPx, QPc, H2, W2);
    // L8: QP -> QA (w2,b2)   [QA := x3_ds,c3_ds]
    navg5v_kernel<<<gdim5(W2, H2), 256, 0, stream>>>(QPx, QPc, w2, b2, QAx, QAc, H2, W2);
    // pool -> eighth
    pool_kernel<<<(int)((2 * n3 + 255) / 256), 256, 0, stream>>>(QAx, QAc, EPx, EPc, H3, W3);
    // L10: EP -> EA (w2,b2)  [EA := x4_ds,c4_ds]
    navg5v_kernel<<<gdim5(W3, H3), 256, 0, stream>>>(EPx, EPc, w2, b2, EAx, EAc, H3, W3);
    // L12: cat(QA, up2(EA)) -> QP (w34,b34)
    navg3_kernel<false, true><<<gdim(W2, H2), blk, 0, stream>>>(
        QAx, QAc, EAx, EAc, w34, b34, QPx, QPc, H2, W2);
    // L14: cat(HP, up2(QP)) -> HA (w23,b23)
    navg3_kernel<false, true><<<gdim(W1, H1), blk, 0, stream>>>(
        HPx, HPc, QPx, QPc, w23, b23, HAx, HAc, H1, W1);
    // L16 + L17 fused: cat(up2(HA), FA) -> full res, then 1x1 w4, fp32 out
    navg3f_kernel<<<dim3(W0 / GTW, H0 / GTH, NB), 256, 0, stream>>>(
        HAx, HAc, FAx, FAc, w12, b12, w4, b4, out, out + n0, H0, W0);
}

// Round 4
// 424.668 us; speedup vs baseline: 1.0124x; 1.0124x over previous
//
#include <hip/hip_runtime.h>

// PretrainedCNN: normalized-convolution U-Net, B=16, 512x640, NC=2.
// Inputs fp32; OUTPUT d_out fp32: xout plane (n0) then cout plane (n0).
// Intermediates fp32 planar [ch][b][h][w], plane stride NB*npix.
// Round 12: revert round-11 regression (waves_per_eu + prefetch: occupancy
// 51->42%, no ILP gain). Structural change instead: the 3-layer fused
// encoder was latency-bound (no pipe >50%, phases serialize with declining
// utilization at 5 blocks/CU). Split: enc12 (L1+L2, halo 4, 20KB LDS ->
// 8 blocks/CU) + navg5p (L3+pool at full res, tile 64x16 -> conv uses all
// 256 threads, 7 blocks/CU). Costs one extra full-res round-trip (~90MB,
// L3-cached). Runtime ws_size check with fallback to fused enc_full.

#define NB 16

typedef __attribute__((ext_vector_type(2))) float f32x2;

__device__ __forceinline__ f32x2 splat2(float s) { f32x2 v = {s, s}; return v; }
__device__ __forceinline__ float frcp(float x) { return __builtin_amdgcn_rcpf(x); }

constexpr int TX = 32, TY = 8;

// ---- shared conv helpers (compact, v_pk_fma_f32 channel-packed) ----
template<int CIN>
__device__ __forceinline__ void conv5x4(const float* sc, const float* sp,
                                        int chStride, int rw,
                                        const float* __restrict__ w,
                                        f32x2 ca[4], f32x2 pa[4]) {
#pragma unroll
    for (int j = 0; j < 4; ++j) { ca[j] = splat2(0.f); pa[j] = splat2(0.f); }
#pragma unroll
    for (int ci = 0; ci < CIN; ++ci) {
#pragma unroll
        for (int kh = 0; kh < 5; ++kh) {
            const float* rc = sc + ci * chStride + kh * rw;
            const float* rp = sp + ci * chStride + kh * rw;
            float cw[8], pw[8];
            *(float4*)&cw[0] = *(const float4*)rc;
            *(float4*)&cw[4] = *(const float4*)(rc + 4);
            *(float4*)&pw[0] = *(const float4*)rp;
            *(float4*)&pw[4] = *(const float4*)(rp + 4);
#pragma unroll
            for (int kw = 0; kw < 5; ++kw) {
                const int q = (ci * 5 + kh) * 5 + kw;
                const f32x2 wv = { w[q], w[CIN * 25 + q] };
#pragma unroll
                for (int j = 0; j < 4; ++j) {
                    ca[j] += splat2(cw[j + kw]) * wv;   // v_pk_fma_f32
                    pa[j] += splat2(pw[j + kw]) * wv;
                }
            }
        }
    }
}

template<int CIN>
__device__ __forceinline__ void conv3x4(const float* sc, const float* sp,
                                        int chStride, int rw,
                                        const float* __restrict__ w,
                                        f32x2 ca[4], f32x2 pa[4]) {
#pragma unroll
    for (int j = 0; j < 4; ++j) { ca[j] = splat2(0.f); pa[j] = splat2(0.f); }
#pragma unroll
    for (int ci = 0; ci < CIN; ++ci) {
#pragma unroll
        for (int kh = 0; kh < 3; ++kh) {
            const float* rc = sc + ci * chStride + kh * rw;
            const float* rp = sp + ci * chStride + kh * rw;
            float cw[6], pw[6];
            *(float4*)&cw[0] = *(const float4*)rc;
            *(float2*)&cw[4] = *(const float2*)(rc + 4);
            *(float4*)&pw[0] = *(const float4*)rp;
            *(float2*)&pw[4] = *(const float2*)(rp + 4);
#pragma unroll
            for (int kw = 0; kw < 3; ++kw) {
                const int q = (ci * 3 + kh) * 3 + kw;
                const f32x2 wv = { w[q], w[CIN * 9 + q] };
#pragma unroll
                for (int j = 0; j < 4; ++j) {
                    ca[j] += splat2(cw[j + kw]) * wv;
                    pa[j] += splat2(pw[j + kw]) * wv;
                }
            }
        }
    }
}

// ================= NEW: enc12 = L1+L2 fused (halo 4) =================
// out tile 32x16 (L2 out); s0 40x24 (stride 44, 11 groups odd); s1 36x20 (stride 36, 9 odd)
constexpr int ATW = 32, ATH = 16;
constexpr int ASW = 40, ASH = 24, ASS = 44;
constexpr int AAW = 36, AAH = 20, AAS = 36;

__global__ __launch_bounds__(256)
void enc12_kernel(const float* __restrict__ x0, const float* __restrict__ c0,
                  const float* __restrict__ w1, const float* __restrict__ b1,
                  const float* __restrict__ w2, const float* __restrict__ b2,
                  float* __restrict__ L2x, float* __restrict__ L2c,
                  int H, int W) {
    __shared__ __align__(16) float s0c[ASH][ASS], s0p[ASH][ASS];            // 8448 B
    __shared__ __align__(16) float s1c[2][AAH][AAS], s1p[2][AAH][AAS];      // 11520 B
    __shared__ float sinvf[4], sbf[4];   // [L1o0, L1o1, L2o0, L2o1]

    const int tid = threadIdx.x;
    const int b = blockIdx.z;
    const int Y0 = blockIdx.y * ATH, X0 = blockIdx.x * ATW;
    const int npix = H * W;
    const size_t bofs = (size_t)b * npix;
    const size_t chs = (size_t)NB * npix;

    const bool interior = (X0 >= 4) && (X0 + ATW + 4 <= W) && (Y0 >= 4) && (Y0 + ATH + 4 <= H);

    if (tid < 4) {
        const int L = tid >> 1, o = tid & 1;
        const float* wl = (L == 0) ? w1 : w2;
        const float* bl = (L == 0) ? b1 : b2;
        const int n = (L == 0) ? 25 : 50;
        float s = 0.f;
        for (int i = 0; i < n; ++i) s += wl[o * n + i];
        sinvf[tid] = 1.f / s;
        sbf[tid] = bl[o];
    }

    // stage 40x24 (halo 4)
    if (interior) {
        const size_t o0 = bofs + (size_t)(Y0 - 4) * W + (X0 - 4);
        for (int i = tid; i < ASH * ASW; i += 256) {
            const int ly = i / ASW, lx = i - ly * ASW;
            const size_t o = o0 + (size_t)ly * W + lx;
            const float cv = c0[o];
            s0c[ly][lx] = cv; s0p[ly][lx] = x0[o] * cv;
        }
    } else {
        for (int i = tid; i < ASH * ASW; i += 256) {
            const int ly = i / ASW, lx = i - ly * ASW;
            const int gy = Y0 + ly - 4, gx = X0 + lx - 4;
            float cv = 0.f, pv = 0.f;
            if (gy >= 0 && gy < H && gx >= 0 && gx < W) {
                const size_t o = bofs + (size_t)gy * W + gx;
                cv = c0[o]; pv = x0[o] * cv;
            }
            s0c[ly][lx] = cv; s0p[ly][lx] = pv;
        }
    }
    __syncthreads();

    // L1: 36x20, CIN=1 -> s1
    if (tid < AAH * (AAW / 4)) {                  // 180 threads
        const int row = tid / (AAW / 4), lx = (tid % (AAW / 4)) * 4;
        f32x2 ca[4], pa[4];
        conv5x4<1>(&s0c[row][lx], &s0p[row][lx], 0, ASS, w1, ca, pa);
        const f32x2 iv = { sinvf[0], sinvf[1] };
        const f32x2 bb = { sbf[0], sbf[1] };
        float cq[2][4], pq[2][4];
        if (interior) {
#pragma unroll
            for (int j = 0; j < 4; ++j) {
                f32x2 r = { frcp(ca[j].x + 1e-20f), frcp(ca[j].y + 1e-20f) };
                const f32x2 xv = pa[j] * r + bb;
                const f32x2 cvv = ca[j] * iv;
                cq[0][j] = cvv.x;            cq[1][j] = cvv.y;
                pq[0][j] = xv.x * cvv.x;     pq[1][j] = xv.y * cvv.y;
            }
        } else {
            const int gy = Y0 + row - 2;
#pragma unroll
            for (int j = 0; j < 4; ++j) {
                const int gx = X0 + lx + j - 2;
                const bool in = (gy >= 0 && gy < H && gx >= 0 && gx < W);
                f32x2 r = { frcp(ca[j].x + 1e-20f), frcp(ca[j].y + 1e-20f) };
                const f32x2 xv = pa[j] * r + bb;
                const f32x2 cvv = ca[j] * iv;
                cq[0][j] = in ? cvv.x : 0.f;            cq[1][j] = in ? cvv.y : 0.f;
                pq[0][j] = in ? xv.x * cvv.x : 0.f;     pq[1][j] = in ? xv.y * cvv.y : 0.f;
            }
        }
#pragma unroll
        for (int o = 0; o < 2; ++o) {
            *(float4*)&s1c[o][row][lx] = make_float4(cq[o][0], cq[o][1], cq[o][2], cq[o][3]);
            *(float4*)&s1p[o][row][lx] = make_float4(pq[o][0], pq[o][1], pq[o][2], pq[o][3]);
        }
    }
    __syncthreads();

    // L2: 32x16, CIN=2 -> global L2x/L2c (always in-image: exact tiling)
    if (tid < ATH * (ATW / 4)) {                  // 128 threads
        const int row = tid >> 3, lx = (tid & 7) * 4;
        f32x2 ca[4], pa[4];
        conv5x4<2>(&s1c[0][row][lx], &s1p[0][row][lx], AAH * AAS, AAS, w2, ca, pa);
        const f32x2 iv = { sinvf[2], sinvf[3] };
        const f32x2 bb = { sbf[2], sbf[3] };
        float xq[2][4], cq[2][4];
#pragma unroll
        for (int j = 0; j < 4; ++j) {
            f32x2 r = { frcp(ca[j].x + 1e-20f), frcp(ca[j].y + 1e-20f) };
            const f32x2 xv = pa[j] * r + bb;
            const f32x2 cvv = ca[j] * iv;
            xq[0][j] = xv.x;  xq[1][j] = xv.y;
            cq[0][j] = cvv.x; cq[1][j] = cvv.y;
        }
        const size_t base = bofs + (size_t)(Y0 + row) * W + (X0 + lx);
#pragma unroll
        for (int o = 0; o < 2; ++o) {
            *(float4*)(L2x + o * chs + base) = make_float4(xq[o][0], xq[o][1], xq[o][2], xq[o][3]);
            *(float4*)(L2c + o * chs + base) = make_float4(cq[o][0], cq[o][1], cq[o][2], cq[o][3]);
        }
    }
}

// ================= NEW: navg5p = L3 + 2x2 pool, full res =================
// tile 64x16, stage 68x20 (stride 68, 17 groups odd); conv uses all 256 threads
constexpr int VTW = 64, VTH = 16, VSW = 68, VSH = 20;

__global__ __launch_bounds__(256)
void navg5p_kernel(const float* __restrict__ xin, const float* __restrict__ cin,
                   const float* __restrict__ w, const float* __restrict__ bias,
                   float* __restrict__ FAx, float* __restrict__ FAc,
                   float* __restrict__ HPx, float* __restrict__ HPc,
                   int H, int W) {
    __shared__ __align__(16) float sc[2][VSH][VSW], sp[2][VSH][VSW];   // 21760 B
    __shared__ float sinvf[2], sbf[2];

    const int tid = threadIdx.x;
    const int b = blockIdx.z;
    const int Y0 = blockIdx.y * VTH, X0 = blockIdx.x * VTW;
    const int npix = H * W;
    const size_t bofs = (size_t)b * npix;
    const size_t chs = (size_t)NB * npix;

    const bool interior = (X0 >= 2) && (X0 + VTW + 2 <= W) && (Y0 >= 2) && (Y0 + VTH + 2 <= H);

    if (tid < 2) {
        float s = 0.f;
        for (int i = 0; i < 50; ++i) s += w[tid * 50 + i];
        sinvf[tid] = 1.f / s;
        sbf[tid] = bias[tid];
    }

    for (int ci = 0; ci < 2; ++ci) {
        const size_t base = (size_t)ci * chs + bofs;
        if (interior) {
            const size_t o0 = base + (size_t)(Y0 - 2) * W + (X0 - 2);
            for (int i = tid; i < VSH * VSW; i += 256) {
                const int ly = i / VSW, lx = i - ly * VSW;
                const size_t o = o0 + (size_t)ly * W + lx;
                const float cv = cin[o];
                sc[ci][ly][lx] = cv; sp[ci][ly][lx] = xin[o] * cv;
            }
        } else {
            for (int i = tid; i < VSH * VSW; i += 256) {
                const int ly = i / VSW, lx = i - ly * VSW;
                const int gy = Y0 + ly - 2, gx = X0 + lx - 2;
                float cv = 0.f, pv = 0.f;
                if (gy >= 0 && gy < H && gx >= 0 && gx < W) {
                    const size_t o = base + (size_t)gy * W + gx;
                    cv = cin[o]; pv = xin[o] * cv;
                }
                sc[ci][ly][lx] = cv; sp[ci][ly][lx] = pv;
            }
        }
    }
    __syncthreads();

    // conv: 64x16 outputs, 4 px/thread -> exactly 256 threads
    const int row = tid >> 4, lx4 = (tid & 15) * 4;
    f32x2 ca[4], pa[4];
    conv5x4<2>(&sc[0][row][lx4], &sp[0][row][lx4], VSH * VSW, VSW, w, ca, pa);

    float xv[2][4], cv[2][4];
#pragma unroll
    for (int j = 0; j < 4; ++j) {
        f32x2 r = { frcp(ca[j].x + 1e-20f), frcp(ca[j].y + 1e-20f) };
        xv[0][j] = pa[j].x * r.x + sbf[0];  xv[1][j] = pa[j].y * r.y + sbf[1];
        cv[0][j] = ca[j].x * sinvf[0];      cv[1][j] = ca[j].y * sinvf[1];
    }
    const size_t base = bofs + (size_t)(Y0 + row) * W + (X0 + lx4);
#pragma unroll
    for (int o = 0; o < 2; ++o) {
        *(float4*)(FAx + o * chs + base) = make_float4(xv[o][0], xv[o][1], xv[o][2], xv[o][3]);
        *(float4*)(FAc + o * chs + base) = make_float4(cv[o][0], cv[o][1], cv[o][2], cv[o][3]);
    }

    // pool 2x2 (first-wins argmax of c): partner row = row^1 -> lane^16
    float pcv[2][4], pxv[2][4];
#pragma unroll
    for (int o = 0; o < 2; ++o)
#pragma unroll
        for (int j = 0; j < 4; ++j) {
            pcv[o][j] = __shfl_xor(cv[o][j], 16);
            pxv[o][j] = __shfl_xor(xv[o][j], 16);
        }
    if ((row & 1) == 0) {
        const int Wh = W >> 1;
        const int np1 = (H >> 1) * Wh;
        const int hy = (Y0 + row) >> 1;
        const int hx0 = (X0 + lx4) >> 1;
#pragma unroll
        for (int o = 0; o < 2; ++o) {
            float bcg[2], bxg[2];
#pragma unroll
            for (int g = 0; g < 2; ++g) {
                const float c00 = cv[o][2 * g], c01 = cv[o][2 * g + 1];
                const float c10 = pcv[o][2 * g], c11 = pcv[o][2 * g + 1];
                const float x00 = xv[o][2 * g], x01 = xv[o][2 * g + 1];
                const float x10 = pxv[o][2 * g], x11 = pxv[o][2 * g + 1];
                float bc = c00, bx = x00;
                if (c01 > bc) { bc = c01; bx = x01; }
                if (c10 > bc) { bc = c10; bx = x10; }
                if (c11 > bc) { bc = c11; bx = x11; }
                bcg[g] = bc * 0.25f; bxg[g] = bx;
            }
            const size_t ho = (size_t)o * NB * np1 + (size_t)b * np1 + (size_t)hy * Wh + hx0;
            *(float2*)(HPc + ho) = make_float2(bcg[0], bcg[1]);
            *(float2*)(HPx + ho) = make_float2(bxg[0], bxg[1]);
        }
    }
}

// ================= FALLBACK: fused full-res encoder (round-10) =================
constexpr int FTW = 32, FTH = 16;
constexpr int FSW = 44, FSH = 28;
constexpr int FAW = 40, FAH = 24;
constexpr int FAS = 44;
constexpr int FBW = 36, FBH = 20;

union EncSmem {
    struct { float c[FSH][FSW]; float p[FSH][FSW]; } s0;
    struct { float c[2][FBH][FBW]; float p[2][FBH][FBW]; } s2;
};

__global__ __launch_bounds__(256)
void enc_full_kernel(const float* __restrict__ x0, const float* __restrict__ c0,
                     const float* __restrict__ w1, const float* __restrict__ b1,
                     const float* __restrict__ w2, const float* __restrict__ b2,
                     const float* __restrict__ w3, const float* __restrict__ b3,
                     float* __restrict__ FAx, float* __restrict__ FAc,
                     float* __restrict__ HPx, float* __restrict__ HPc,
                     int H, int W) {
    __shared__ __align__(16) EncSmem u;
    __shared__ __align__(16) float s1c[2][FAH][FAS], s1p[2][FAH][FAS];
    __shared__ float sinvf[6], sbf[6];

    const int tid = threadIdx.x;
    const int b = blockIdx.z;
    const int Y0 = blockIdx.y * FTH, X0 = blockIdx.x * FTW;
    const int npix = H * W;
    const size_t bofs = (size_t)b * npix;
    const size_t chs = (size_t)NB * npix;

    const bool interior = (X0 >= 6) && (X0 + FTW + 6 <= W) && (Y0 >= 6) && (Y0 + FTH + 6 <= H);

    if (tid < 6) {
        const int L = tid >> 1, o = tid & 1;
        const float* wl = (L == 0) ? w1 : (L == 1) ? w2 : w3;
        const float* bl = (L == 0) ? b1 : (L == 1) ? b2 : b3;
        const int n = (L == 0) ? 25 : 50;
        float s = 0.f;
        for (int i = 0; i < n; ++i) s += wl[o * n + i];
        sinvf[tid] = 1.f / s;
        sbf[tid] = bl[o];
    }

    if (interior) {
        const size_t o0 = bofs + (size_t)(Y0 - 6) * W + (X0 - 6);
        for (int i = tid; i < FSH * FSW; i += 256) {
            const int ly = i / FSW, lx = i - ly * FSW;
            const size_t o = o0 + (size_t)ly * W + lx;
            const float cv = c0[o];
            u.s0.c[ly][lx] = cv; u.s0.p[ly][lx] = x0[o] * cv;
        }
    } else {
        for (int i = tid; i < FSH * FSW; i += 256) {
            const int ly = i / FSW, lx = i - ly * FSW;
            const int gy = Y0 + ly - 6, gx = X0 + lx - 6;
            float cv = 0.f, pv = 0.f;
            if (gy >= 0 && gy < H && gx >= 0 && gx < W) {
                const size_t o = bofs + (size_t)gy * W + gx;
                cv = c0[o]; pv = x0[o] * cv;
            }
            u.s0.c[ly][lx] = cv; u.s0.p[ly][lx] = pv;
        }
    }
    __syncthreads();

    if (tid < FAH * (FAW / 4)) {
        const int row = tid / (FAW / 4), lx = (tid % (FAW / 4)) * 4;
        f32x2 ca[4], pa[4];
        conv5x4<1>(&u.s0.c[row][lx], &u.s0.p[row][lx], 0, FSW, w1, ca, pa);
        const f32x2 iv = { sinvf[0], sinvf[1] };
        const f32x2 bb = { sbf[0], sbf[1] };
        float cq[2][4], pq[2][4];
        if (interior) {
#pragma unroll
            for (int j = 0; j < 4; ++j) {
                f32x2 r = { frcp(ca[j].x + 1e-20f), frcp(ca[j].y + 1e-20f) };
                const f32x2 xv = pa[j] * r + bb;
                const f32x2 cvv = ca[j] * iv;
                cq[0][j] = cvv.x;            cq[1][j] = cvv.y;
                pq[0][j] = xv.x * cvv.x;     pq[1][j] = xv.y * cvv.y;
            }
        } else {
            const int gy = Y0 + row - 4;
#pragma unroll
            for (int j = 0; j < 4; ++j) {
                const int gx = X0 + lx + j - 4;
                const bool in = (gy >= 0 && gy < H && gx >= 0 && gx < W);
                f32x2 r = { frcp(ca[j].x + 1e-20f), frcp(ca[j].y + 1e-20f) };
                const f32x2 xv = pa[j] * r + bb;
                const f32x2 cvv = ca[j] * iv;
                cq[0][j] = in ? cvv.x : 0.f;            cq[1][j] = in ? cvv.y : 0.f;
                pq[0][j] = in ? xv.x * cvv.x : 0.f;     pq[1][j] = in ? xv.y * cvv.y : 0.f;
            }
        }
#pragma unroll
        for (int o = 0; o < 2; ++o) {
            *(float4*)&s1c[o][row][lx] = make_float4(cq[o][0], cq[o][1], cq[o][2], cq[o][3]);
            *(float4*)&s1p[o][row][lx] = make_float4(pq[o][0], pq[o][1], pq[o][2], pq[o][3]);
        }
    }
    __syncthreads();

    if (tid < FBH * (FBW / 4)) {
        const int row = tid / (FBW / 4), lx = (tid % (FBW / 4)) * 4;
        f32x2 ca[4], pa[4];
        conv5x4<2>(&s1c[0][row][lx], &s1p[0][row][lx], FAH * FAS, FAS, w2, ca, pa);
        const f32x2 iv = { sinvf[2], sinvf[3] };
        const f32x2 bb = { sbf[2], sbf[3] };
        float cq[2][4], pq[2][4];
        if (interior) {
#pragma unroll
            for (int j = 0; j < 4; ++j) {
                f32x2 r = { frcp(ca[j].x + 1e-20f), frcp(ca[j].y + 1e-20f) };
                const f32x2 xv = pa[j] * r + bb;
                const f32x2 cvv = ca[j] * iv;
                cq[0][j] = cvv.x;            cq[1][j] = cvv.y;
                pq[0][j] = xv.x * cvv.x;     pq[1][j] = xv.y * cvv.y;
            }
        } else {
            const int gy = Y0 + row - 2;
#pragma unroll
            for (int j = 0; j < 4; ++j) {
                const int gx = X0 + lx + j - 2;
                const bool in = (gy >= 0 && gy < H && gx >= 0 && gx < W);
                f32x2 r = { frcp(ca[j].x + 1e-20f), frcp(ca[j].y + 1e-20f) };
                const f32x2 xv = pa[j] * r + bb;
                const f32x2 cvv = ca[j] * iv;
                cq[0][j] = in ? cvv.x : 0.f;            cq[1][j] = in ? cvv.y : 0.f;
                pq[0][j] = in ? xv.x * cvv.x : 0.f;     pq[1][j] = in ? xv.y * cvv.y : 0.f;
            }
        }
#pragma unroll
        for (int o = 0; o < 2; ++o) {
            *(float4*)&u.s2.c[o][row][lx] = make_float4(cq[o][0], cq[o][1], cq[o][2], cq[o][3]);
            *(float4*)&u.s2.p[o][row][lx] = make_float4(pq[o][0], pq[o][1], pq[o][2], pq[o][3]);
        }
    }
    __syncthreads();

    if (tid < FTH * (FTW / 4)) {
        const int row = tid / (FTW / 4), lx = (tid % (FTW / 4)) * 4;
        f32x2 ca[4], pa[4];
        conv5x4<2>(&u.s2.c[0][row][lx], &u.s2.p[0][row][lx], FBH * FBW, FBW, w3, ca, pa);
        const f32x2 iv = { sinvf[4], sinvf[5] };
        const f32x2 bb = { sbf[4], sbf[5] };
        float xv[2][4], cv[2][4];
#pragma unroll
        for (int j = 0; j < 4; ++j) {
            f32x2 r = { frcp(ca[j].x + 1e-20f), frcp(ca[j].y + 1e-20f) };
            const f32x2 x2 = pa[j] * r + bb;
            const f32x2 c2 = ca[j] * iv;
            xv[0][j] = x2.x; xv[1][j] = x2.y;
            cv[0][j] = c2.x; cv[1][j] = c2.y;
        }
        const int gy = Y0 + row;
        const size_t base = bofs + (size_t)gy * W + (X0 + lx);
#pragma unroll
        for (int o = 0; o < 2; ++o) {
            *(float4*)(FAx + o * chs + base) = make_float4(xv[o][0], xv[o][1], xv[o][2], xv[o][3]);
            *(float4*)(FAc + o * chs + base) = make_float4(cv[o][0], cv[o][1], cv[o][2], cv[o][3]);
        }
        float pcv[2][4], pxv[2][4];
#pragma unroll
        for (int o = 0; o < 2; ++o)
#pragma unroll
            for (int j = 0; j < 4; ++j) {
                pcv[o][j] = __shfl_xor(cv[o][j], 8);
                pxv[o][j] = __shfl_xor(xv[o][j], 8);
            }
        if ((row & 1) == 0) {
            const int Wh = W >> 1;
            const int np1 = (H >> 1) * Wh;
            const int hy = (Y0 + row) >> 1;
            const int hx0 = (X0 + lx) >> 1;
#pragma unroll
            for (int o = 0; o < 2; ++o)
#pragma unroll
                for (int g = 0; g < 2; ++g) {
                    const float c00 = cv[o][2 * g], c01 = cv[o][2 * g + 1];
                    const float c10 = pcv[o][2 * g], c11 = pcv[o][2 * g + 1];
                    const float x00 = xv[o][2 * g], x01 = xv[o][2 * g + 1];
                    const float x10 = pxv[o][2 * g], x11 = pxv[o][2 * g + 1];
                    float bc = c00, bx = x00;
                    if (c01 > bc) { bc = c01; bx = x01; }
                    if (c10 > bc) { bc = c10; bx = x10; }
                    if (c11 > bc) { bc = c11; bx = x11; }
                    const size_t ho = (size_t)o * NB * np1 + (size_t)b * np1 + (size_t)hy * Wh + hx0 + g;
                    HPc[ho] = bc * 0.25f;
                    HPx[ho] = bx;
                }
        }
    }
}

// ================= vectorized sub-res 5x5 (4 px/thread) =================
__global__ __launch_bounds__(256)
void navg5v_kernel(const float* __restrict__ xin, const float* __restrict__ cin,
                   const float* __restrict__ w, const float* __restrict__ bias,
                   float* __restrict__ xout, float* __restrict__ cout,
                   int H, int W) {
    __shared__ __align__(16) float sc[2][VSH][VSW], sp[2][VSH][VSW];
    __shared__ float sinvf[2];

    const int tid = threadIdx.x;
    const int b = blockIdx.z;
    const int Y0 = blockIdx.y * VTH, X0 = blockIdx.x * VTW;
    const int npix = H * W;
    const size_t bofs = (size_t)b * npix;
    const size_t chs = (size_t)NB * npix;

    if (tid < 2) {
        float s = 0.f;
        for (int i = 0; i < 50; ++i) s += w[tid * 50 + i];
        sinvf[tid] = 1.f / s;
    }

    for (int ci = 0; ci < 2; ++ci) {
        const size_t base = (size_t)ci * chs + bofs;
        for (int i = tid; i < VSH * VSW; i += 256) {
            const int ly = i / VSW, lx = i - ly * VSW;
            const int gy = Y0 + ly - 2, gx = X0 + lx - 2;
            float cv = 0.f, pv = 0.f;
            if (gy >= 0 && gy < H && gx >= 0 && gx < W) {
                const size_t o = base + (size_t)gy * W + gx;
                cv = cin[o]; pv = xin[o] * cv;
            }
            sc[ci][ly][lx] = cv; sp[ci][ly][lx] = pv;
        }
    }
    __syncthreads();

    const int row = tid >> 4, lx4 = (tid & 15) * 4;
    f32x2 ca[4], pa[4];
    conv5x4<2>(&sc[0][row][lx4], &sp[0][row][lx4], VSH * VSW, VSW, w, ca, pa);

    const int gy = Y0 + row, gx = X0 + lx4;
    if (gy < H && gx < W) {
        const float bb0 = bias[0], bb1 = bias[1];
        float xq[2][4], cq[2][4];
#pragma unroll
        for (int j = 0; j < 4; ++j) {
            f32x2 r = { frcp(ca[j].x + 1e-20f), frcp(ca[j].y + 1e-20f) };
            xq[0][j] = pa[j].x * r.x + bb0;  xq[1][j] = pa[j].y * r.y + bb1;
            cq[0][j] = ca[j].x * sinvf[0];   cq[1][j] = ca[j].y * sinvf[1];
        }
        const size_t off = bofs + (size_t)gy * W + gx;
#pragma unroll
        for (int o = 0; o < 2; ++o) {
            *(float4*)(xout + o * chs + off) = make_float4(xq[o][0], xq[o][1], xq[o][2], xq[o][3]);
            *(float4*)(cout + o * chs + off) = make_float4(cq[o][0], cq[o][1], cq[o][2], cq[o][3]);
        }
    }
}

__global__ void pool_kernel(const float* __restrict__ xin, const float* __restrict__ cin,
                            float* __restrict__ xout, float* __restrict__ cout,
                            int Hh, int Wh) {
    const int nplane = Hh * Wh;
    const int total = 2 * NB * nplane;
    const int idx = blockIdx.x * blockDim.x + threadIdx.x;
    if (idx >= total) return;
    const int p = idx / nplane;
    const int q = idx - p * nplane;
    const int h = q / Wh, wc = q - h * Wh;
    const int Wf = 2 * Wh;
    const size_t ibase = (size_t)p * 4 * nplane + (size_t)(2 * h) * Wf + 2 * wc;
    const float c00 = cin[ibase], c01 = cin[ibase + 1];
    const float c10 = cin[ibase + Wf], c11 = cin[ibase + Wf + 1];
    float best = c00; size_t boff = ibase;
    if (c01 > best) { best = c01; boff = ibase + 1; }
    if (c10 > best) { best = c10; boff = ibase + Wf; }
    if (c11 > best) { best = c11; boff = ibase + Wf + 1; }
    cout[idx] = best * 0.25f;
    xout[idx] = xin[boff];
}

// ================= sub-res 3x3 cat kernels (1 px/thread) ======
template<bool UPA, bool UPB>
__global__ __launch_bounds__(256)
void navg3_kernel(const float* __restrict__ xA, const float* __restrict__ cA,
                  const float* __restrict__ xB, const float* __restrict__ cB,
                  const float* __restrict__ w, const float* __restrict__ bias,
                  float* __restrict__ xout, float* __restrict__ cout,
                  int H, int W) {
    __shared__ float sc[4][TY + 2][TX + 2];
    __shared__ float sp[4][TY + 2][TX + 2];
    __shared__ float sinvf[2];

    const int b = blockIdx.z;
    const int npix = H * W;
    const size_t chs = (size_t)NB * npix;
    const int tid = threadIdx.y * TX + threadIdx.x;

    if (tid < 2) {
        float s = 0.f;
        for (int i = 0; i < 36; ++i) s += w[tid * 36 + i];
        sinvf[tid] = 1.f / s;
    }

    const int y0 = blockIdx.y * TY - 1;
    const int x0 = blockIdx.x * TX - 1;
    const int Ws2 = W >> 1;
    const int npixS = (H >> 1) * Ws2;

#pragma unroll
    for (int ch = 0; ch < 4; ++ch) {
        const bool up = (ch < 2) ? UPA : UPB;
        const float* xs = (ch < 2) ? xA : xB;
        const float* cs = (ch < 2) ? cA : cB;
        const int sch = ch & 1;
        const size_t base = up ? ((size_t)sch * NB * npixS + (size_t)b * npixS)
                               : ((size_t)sch * chs + (size_t)b * npix);
        for (int i = tid; i < (TY + 2) * (TX + 2); i += 256) {
            const int ly = i / (TX + 2), lx = i % (TX + 2);
            const int gy = y0 + ly, gx = x0 + lx;
            float cv = 0.f, pv = 0.f;
            if (gy >= 0 && gy < H && gx >= 0 && gx < W) {
                const size_t o = up ? (base + (size_t)(gy >> 1) * Ws2 + (gx >> 1))
                                    : (base + (size_t)gy * W + gx);
                cv = cs[o];
                pv = xs[o] * cv;
            }
            sc[ch][ly][lx] = cv;
            sp[ch][ly][lx] = pv;
        }
    }
    __syncthreads();

    const int gh = blockIdx.y * TY + threadIdx.y;
    const int gw = blockIdx.x * TX + threadIdx.x;
    if (gh < H && gw < W) {
        const size_t off = (size_t)b * npix + (size_t)gh * W + gw;
        f32x2 ca = splat2(0.f), pa = splat2(0.f);
#pragma unroll
        for (int ci = 0; ci < 4; ++ci)
#pragma unroll
            for (int kh = 0; kh < 3; ++kh)
#pragma unroll
                for (int kw = 0; kw < 3; ++kw) {
                    const int q = (ci * 3 + kh) * 3 + kw;
                    const f32x2 wv = { w[q], w[36 + q] };
                    ca += splat2(sc[ci][threadIdx.y + kh][threadIdx.x + kw]) * wv;
                    pa += splat2(sp[ci][threadIdx.y + kh][threadIdx.x + kw]) * wv;
                }
        xout[off]       = pa.x * frcp(ca.x + 1e-20f) + bias[0];
        xout[chs + off] = pa.y * frcp(ca.y + 1e-20f) + bias[1];
        cout[off]       = ca.x * sinvf[0];
        cout[chs + off] = ca.y * sinvf[1];
    }
}

// ================= final fused layer: cat(up2(HA), FA) -> 3x3 -> 1x1 =======
constexpr int GTW = 32, GTH = 32, GSW = 34, GSH = 34, GSS = 36;

__global__ __launch_bounds__(256)
void navg3f_kernel(const float* __restrict__ xA, const float* __restrict__ cA,
                   const float* __restrict__ xB, const float* __restrict__ cB,
                   const float* __restrict__ w, const float* __restrict__ bias,
                   const float* __restrict__ w4, const float* __restrict__ b4,
                   float* __restrict__ xout, float* __restrict__ cout,
                   int H, int W) {
    __shared__ __align__(16) float sc[4][GSH][GSS], sp[4][GSH][GSS];
    __shared__ float sinvf[2];

    const int tid = threadIdx.x;
    const int b = blockIdx.z;
    const int Y0 = blockIdx.y * GTH, X0 = blockIdx.x * GTW;
    const int npix = H * W;
    const size_t bofs = (size_t)b * npix;
    const size_t chs = (size_t)NB * npix;
    const int Ws2 = W >> 1;
    const int npixS = (H >> 1) * Ws2;

    if (tid < 2) {
        float s = 0.f;
        for (int i = 0; i < 36; ++i) s += w[tid * 36 + i];
        sinvf[tid] = 1.f / s;
    }

#pragma unroll
    for (int ch = 0; ch < 4; ++ch) {
        const bool up = (ch < 2);
        const float* xs = up ? xA : xB;
        const float* cs = up ? cA : cB;
        const int sch = ch & 1;
        const size_t base = up ? ((size_t)sch * NB * npixS + (size_t)b * npixS)
                               : ((size_t)sch * chs + bofs);
        for (int i = tid; i < GSH * GSW; i += 256) {
            const int ly = i / GSW, lx = i - ly * GSW;
            const int gy = Y0 + ly - 1, gx = X0 + lx - 1;
            float cv = 0.f, pv = 0.f;
            if (gy >= 0 && gy < H && gx >= 0 && gx < W) {
                const size_t o = up ? (base + (size_t)(gy >> 1) * Ws2 + (gx >> 1))
                                    : (base + (size_t)gy * W + gx);
                cv = cs[o]; pv = xs[o] * cv;
            }
            sc[ch][ly][lx] = cv; sp[ch][ly][lx] = pv;
        }
    }
    __syncthreads();

    const int row = tid >> 3, lx4 = (tid & 7) * 4;
    f32x2 ca[4], pa[4];
    conv3x4<4>(&sc[0][row][lx4], &sp[0][row][lx4], GSH * GSS, GSS, w, ca, pa);

    const float w40 = w4[0], w41 = w4[1], b40 = b4[0];
    const float inv4 = frcp(w40 + w41);
    const float bb0 = bias[0], bb1 = bias[1];
    float xq[4], cq[4];
#pragma unroll
    for (int j = 0; j < 4; ++j) {
        const float xv0 = pa[j].x * frcp(ca[j].x + 1e-20f) + bb0;
        const float xv1 = pa[j].y * frcp(ca[j].y + 1e-20f) + bb1;
        const float cv0 = ca[j].x * sinvf[0];
        const float cv1 = ca[j].y * sinvf[1];
        const float ca4 = w40 * cv0 + w41 * cv1;
        xq[j] = (w40 * xv0 * cv0 + w41 * xv1 * cv1) * frcp(ca4 + 1e-20f) + b40;
        cq[j] = ca4 * inv4;
    }
    const size_t off = bofs + (size_t)(Y0 + row) * W + (X0 + lx4);
    *(float4*)(xout + off) = make_float4(xq[0], xq[1], xq[2], xq[3]);
    *(float4*)(cout + off) = make_float4(cq[0], cq[1], cq[2], cq[3]);
}

extern "C" void kernel_launch(void* const* d_in, const int* in_sizes, int n_in,
                              void* d_out, int out_size, void* d_ws, size_t ws_size,
                              hipStream_t stream) {
    const float* x0  = (const float*)d_in[0];
    const float* c0  = (const float*)d_in[1];
    const float* w1  = (const float*)d_in[2];
    const float* w2  = (const float*)d_in[3];
    const float* w3  = (const float*)d_in[4];
    const float* w4  = (const float*)d_in[5];
    const float* w34 = (const float*)d_in[6];
    const float* w23 = (const float*)d_in[7];
    const float* w12 = (const float*)d_in[8];
    const float* b1  = (const float*)d_in[9];
    const float* b2  = (const float*)d_in[10];
    const float* b3  = (const float*)d_in[11];
    const float* b4  = (const float*)d_in[12];
    const float* b34 = (const float*)d_in[13];
    const float* b23 = (const float*)d_in[14];
    const float* b12 = (const float*)d_in[15];

    float* out = (float*)d_out;   // fp32: xout plane then cout plane

    const int H0 = 512, W0 = 640, H1 = 256, W1 = 320, H2 = 128, W2 = 160, H3 = 64, W3 = 80;
    const size_t n0 = (size_t)NB * H0 * W0;
    const size_t n1 = n0 / 4, n2 = n0 / 16, n3 = n0 / 64;

    const size_t arena = 8 * n1 + 8 * n2 + 8 * n3;
    const bool split_enc = ws_size >= (8 * n0 + arena) * sizeof(float);

    float* ws = (float*)d_ws;
    float* FAx = ws;            // x1 (2ch) -- persists to the end
    float* FAc = ws + 2 * n0;   // c1 (2ch)
    float* L2x = nullptr;
    float* L2c = nullptr;
    float* sub;
    if (split_enc) {
        L2x = ws + 4 * n0;      // L2 output x (2ch)
        L2c = ws + 6 * n0;      // L2 output c (2ch)
        sub = ws + 8 * n0;
    } else {
        sub = ws + 4 * n0;
    }
    float* HPx = sub;               sub += 2 * n1;
    float* HPc = sub;               sub += 2 * n1;
    float* HAx = sub;               sub += 2 * n1;
    float* HAc = sub;               sub += 2 * n1;
    float* QPx = sub;               sub += 2 * n2;
    float* QPc = sub;               sub += 2 * n2;
    float* QAx = sub;               sub += 2 * n2;
    float* QAc = sub;               sub += 2 * n2;
    float* EPx = sub;               sub += 2 * n3;
    float* EPc = sub;               sub += 2 * n3;
    float* EAx = sub;               sub += 2 * n3;
    float* EAc = sub;               sub += 2 * n3;

    dim3 blk(TX, TY);
    auto gdim  = [](int W, int H) { return dim3((W + TX - 1) / TX, (H + TY - 1) / TY, NB); };
    auto gdim5 = [](int W, int H) { return dim3((W + VTW - 1) / VTW, (H + VTH - 1) / VTH, NB); };

    if (split_enc) {
        // L1+L2 fused -> L2x/L2c; then L3+pool -> FA + HP
        enc12_kernel<<<dim3(W0 / ATW, H0 / ATH, NB), 256, 0, stream>>>(
            x0, c0, w1, b1, w2, b2, L2x, L2c, H0, W0);
        navg5p_kernel<<<dim3(W0 / VTW, H0 / VTH, NB), 256, 0, stream>>>(
            L2x, L2c, w3, b3, FAx, FAc, HPx, HPc, H0, W0);
    } else {
        enc_full_kernel<<<dim3(W0 / FTW, H0 / FTH, NB), 256, 0, stream>>>(
            x0, c0, w1, b1, w2, b2, w3, b3, FAx, FAc, HPx, HPc, H0, W0);
    }

    // L5: HP -> HA (w2,b2)
    navg5v_kernel<<<gdim5(W1, H1), 256, 0, stream>>>(HPx, HPc, w2, b2, HAx, HAc, H1, W1);
    // L6: HA -> HP (w3,b3)   [HP := x2_ds,c2_ds]
    navg5v_kernel<<<gdim5(W1, H1), 256, 0, stream>>>(HAx, HAc, w3, b3, HPx, HPc, H1, W1);
    // pool -> quarter
    pool_kernel<<<(int)((2 * n2 + 255) / 256), 256, 0, stream>>>(HPx, HPc, QPx, QPc, H2, W2);
    // L8: QP -> QA (w2,b2)   [QA := x3_ds,c3_ds]
    navg5v_kernel<<<gdim5(W2, H2), 256, 0, stream>>>(QPx, QPc, w2, b2, QAx, QAc, H2, W2);
    // pool -> eighth
    pool_kernel<<<(int)((2 * n3 + 255) / 256), 256, 0, stream>>>(QAx, QAc, EPx, EPc, H3, W3);
    // L10: EP -> EA (w2,b2)  [EA := x4_ds,c4_ds]
    navg5v_kernel<<<gdim5(W3, H3), 256, 0, stream>>>(EPx, EPc, w2, b2, EAx, EAc, H3, W3);
    // L12: cat(QA, up2(EA)) -> QP (w34,b34)
    navg3_kernel<false, true><<<gdim(W2, H2), blk, 0, stream>>>(
        QAx, QAc, EAx, EAc, w34, b34, QPx, QPc, H2, W2);
    // L14: cat(HP, up2(QP)) -> HA (w23,b23)
    navg3_kernel<false, true><<<gdim(W1, H1), blk, 0, stream>>>(
        HPx, HPc, QPx, QPc, w23, b23, HAx, HAc, H1, W1);
    // L16 + L17 fused: cat(up2(HA), FA) -> full res, then 1x1 w4, fp32 out
    navg3f_kernel<<<dim3(W0 / GTW, H0 / GTH, NB), 256, 0, stream>>>(
        HAx, HAc, FAx, FAc, w12, b12, w4, b4, out, out + n0, H0, W0);
}

// Round 5
// 404.832 us; speedup vs baseline: 1.0620x; 1.0490x over previous
//
#include <hip/hip_runtime.h>

// PretrainedCNN: normalized-convolution U-Net, B=16, 512x640, NC=2.
// Inputs fp32; OUTPUT d_out fp32: xout plane (n0) then cout plane (n0).
// Intermediates fp32 planar [ch][b][h][w], plane stride NB*npix.
// Round 13: (1) L6/L8 use navg5p (conv+pool fused) -> 2 pool launches and
// ~33MB traffic removed; navg5p gains output guards for non-exact tiles.
// (2) enc12 interior stage -> single-pass float4 (window starts 16B-aligned;
// 240 threads, 1 iter, b128 LDS writes; was 3.75 scalar iters). (3) navg5
// interior stage -> float2 (8B-aligned window, half the instructions).
// (4) L14 -> navg3v: 4px/thread conv3x4 (was 72 scalar LDS reads/px).

#define NB 16

typedef __attribute__((ext_vector_type(2))) float f32x2;

__device__ __forceinline__ f32x2 splat2(float s) { f32x2 v = {s, s}; return v; }
__device__ __forceinline__ float frcp(float x) { return __builtin_amdgcn_rcpf(x); }

constexpr int TX = 32, TY = 8;

// ---- shared conv helpers (compact, v_pk_fma_f32 channel-packed) ----
template<int CIN>
__device__ __forceinline__ void conv5x4(const float* sc, const float* sp,
                                        int chStride, int rw,
                                        const float* __restrict__ w,
                                        f32x2 ca[4], f32x2 pa[4]) {
#pragma unroll
    for (int j = 0; j < 4; ++j) { ca[j] = splat2(0.f); pa[j] = splat2(0.f); }
#pragma unroll
    for (int ci = 0; ci < CIN; ++ci) {
#pragma unroll
        for (int kh = 0; kh < 5; ++kh) {
            const float* rc = sc + ci * chStride + kh * rw;
            const float* rp = sp + ci * chStride + kh * rw;
            float cw[8], pw[8];
            *(float4*)&cw[0] = *(const float4*)rc;
            *(float4*)&cw[4] = *(const float4*)(rc + 4);
            *(float4*)&pw[0] = *(const float4*)rp;
            *(float4*)&pw[4] = *(const float4*)(rp + 4);
#pragma unroll
            for (int kw = 0; kw < 5; ++kw) {
                const int q = (ci * 5 + kh) * 5 + kw;
                const f32x2 wv = { w[q], w[CIN * 25 + q] };
#pragma unroll
                for (int j = 0; j < 4; ++j) {
                    ca[j] += splat2(cw[j + kw]) * wv;   // v_pk_fma_f32
                    pa[j] += splat2(pw[j + kw]) * wv;
                }
            }
        }
    }
}

template<int CIN>
__device__ __forceinline__ void conv3x4(const float* sc, const float* sp,
                                        int chStride, int rw,
                                        const float* __restrict__ w,
                                        f32x2 ca[4], f32x2 pa[4]) {
#pragma unroll
    for (int j = 0; j < 4; ++j) { ca[j] = splat2(0.f); pa[j] = splat2(0.f); }
#pragma unroll
    for (int ci = 0; ci < CIN; ++ci) {
#pragma unroll
        for (int kh = 0; kh < 3; ++kh) {
            const float* rc = sc + ci * chStride + kh * rw;
            const float* rp = sp + ci * chStride + kh * rw;
            float cw[6], pw[6];
            *(float4*)&cw[0] = *(const float4*)rc;
            *(float2*)&cw[4] = *(const float2*)(rc + 4);
            *(float4*)&pw[0] = *(const float4*)rp;
            *(float2*)&pw[4] = *(const float2*)(rp + 4);
#pragma unroll
            for (int kw = 0; kw < 3; ++kw) {
                const int q = (ci * 3 + kh) * 3 + kw;
                const f32x2 wv = { w[q], w[CIN * 9 + q] };
#pragma unroll
                for (int j = 0; j < 4; ++j) {
                    ca[j] += splat2(cw[j + kw]) * wv;
                    pa[j] += splat2(pw[j + kw]) * wv;
                }
            }
        }
    }
}

// ================= enc12 = L1+L2 fused (halo 4) =================
constexpr int ATW = 32, ATH = 16;
constexpr int ASW = 40, ASH = 24, ASS = 44;
constexpr int AAW = 36, AAH = 20, AAS = 36;

__global__ __launch_bounds__(256)
void enc12_kernel(const float* __restrict__ x0, const float* __restrict__ c0,
                  const float* __restrict__ w1, const float* __restrict__ b1,
                  const float* __restrict__ w2, const float* __restrict__ b2,
                  float* __restrict__ L2x, float* __restrict__ L2c,
                  int H, int W) {
    __shared__ __align__(16) float s0c[ASH][ASS], s0p[ASH][ASS];            // 8448 B
    __shared__ __align__(16) float s1c[2][AAH][AAS], s1p[2][AAH][AAS];      // 11520 B
    __shared__ float sinvf[4], sbf[4];

    const int tid = threadIdx.x;
    const int b = blockIdx.z;
    const int Y0 = blockIdx.y * ATH, X0 = blockIdx.x * ATW;
    const int npix = H * W;
    const size_t bofs = (size_t)b * npix;
    const size_t chs = (size_t)NB * npix;

    const bool interior = (X0 >= 4) && (X0 + ATW + 4 <= W) && (Y0 >= 4) && (Y0 + ATH + 4 <= H);

    if (tid < 4) {
        const int L = tid >> 1, o = tid & 1;
        const float* wl = (L == 0) ? w1 : w2;
        const float* bl = (L == 0) ? b1 : b2;
        const int n = (L == 0) ? 25 : 50;
        float s = 0.f;
        for (int i = 0; i < n; ++i) s += wl[o * n + i];
        sinvf[tid] = 1.f / s;
        sbf[tid] = bl[o];
    }

    // stage 40x24 (halo 4)
    if (interior) {
        // X0-4 is 16B-aligned (X0 mult of 32): single-pass float4 stage.
        if (tid < ASH * (ASW / 4)) {       // 240 threads, 1 iteration
            const int row = tid / (ASW / 4), c4 = tid - row * (ASW / 4);
            const size_t o = bofs + (size_t)(Y0 - 4 + row) * W + (X0 - 4) + c4 * 4;
            const float4 cv = *(const float4*)(c0 + o);
            const float4 xv = *(const float4*)(x0 + o);
            *(float4*)&s0c[row][c4 * 4] = cv;
            *(float4*)&s0p[row][c4 * 4] = make_float4(xv.x * cv.x, xv.y * cv.y,
                                                      xv.z * cv.z, xv.w * cv.w);
        }
    } else {
        for (int i = tid; i < ASH * ASW; i += 256) {
            const int ly = i / ASW, lx = i - ly * ASW;
            const int gy = Y0 + ly - 4, gx = X0 + lx - 4;
            float cv = 0.f, pv = 0.f;
            if (gy >= 0 && gy < H && gx >= 0 && gx < W) {
                const size_t o = bofs + (size_t)gy * W + gx;
                cv = c0[o]; pv = x0[o] * cv;
            }
            s0c[ly][lx] = cv; s0p[ly][lx] = pv;
        }
    }
    __syncthreads();

    // L1: 36x20, CIN=1 -> s1
    if (tid < AAH * (AAW / 4)) {                  // 180 threads
        const int row = tid / (AAW / 4), lx = (tid % (AAW / 4)) * 4;
        f32x2 ca[4], pa[4];
        conv5x4<1>(&s0c[row][lx], &s0p[row][lx], 0, ASS, w1, ca, pa);
        const f32x2 iv = { sinvf[0], sinvf[1] };
        const f32x2 bb = { sbf[0], sbf[1] };
        float cq[2][4], pq[2][4];
        if (interior) {
#pragma unroll
            for (int j = 0; j < 4; ++j) {
                f32x2 r = { frcp(ca[j].x + 1e-20f), frcp(ca[j].y + 1e-20f) };
                const f32x2 xv = pa[j] * r + bb;
                const f32x2 cvv = ca[j] * iv;
                cq[0][j] = cvv.x;            cq[1][j] = cvv.y;
                pq[0][j] = xv.x * cvv.x;     pq[1][j] = xv.y * cvv.y;
            }
        } else {
            const int gy = Y0 + row - 2;
#pragma unroll
            for (int j = 0; j < 4; ++j) {
                const int gx = X0 + lx + j - 2;
                const bool in = (gy >= 0 && gy < H && gx >= 0 && gx < W);
                f32x2 r = { frcp(ca[j].x + 1e-20f), frcp(ca[j].y + 1e-20f) };
                const f32x2 xv = pa[j] * r + bb;
                const f32x2 cvv = ca[j] * iv;
                cq[0][j] = in ? cvv.x : 0.f;            cq[1][j] = in ? cvv.y : 0.f;
                pq[0][j] = in ? xv.x * cvv.x : 0.f;     pq[1][j] = in ? xv.y * cvv.y : 0.f;
            }
        }
#pragma unroll
        for (int o = 0; o < 2; ++o) {
            *(float4*)&s1c[o][row][lx] = make_float4(cq[o][0], cq[o][1], cq[o][2], cq[o][3]);
            *(float4*)&s1p[o][row][lx] = make_float4(pq[o][0], pq[o][1], pq[o][2], pq[o][3]);
        }
    }
    __syncthreads();

    // L2: 32x16, CIN=2 -> global (exact tiling at full res)
    if (tid < ATH * (ATW / 4)) {                  // 128 threads
        const int row = tid >> 3, lx = (tid & 7) * 4;
        f32x2 ca[4], pa[4];
        conv5x4<2>(&s1c[0][row][lx], &s1p[0][row][lx], AAH * AAS, AAS, w2, ca, pa);
        const f32x2 iv = { sinvf[2], sinvf[3] };
        const f32x2 bb = { sbf[2], sbf[3] };
        float xq[2][4], cq[2][4];
#pragma unroll
        for (int j = 0; j < 4; ++j) {
            f32x2 r = { frcp(ca[j].x + 1e-20f), frcp(ca[j].y + 1e-20f) };
            const f32x2 xv = pa[j] * r + bb;
            const f32x2 cvv = ca[j] * iv;
            xq[0][j] = xv.x;  xq[1][j] = xv.y;
            cq[0][j] = cvv.x; cq[1][j] = cvv.y;
        }
        const size_t base = bofs + (size_t)(Y0 + row) * W + (X0 + lx);
#pragma unroll
        for (int o = 0; o < 2; ++o) {
            *(float4*)(L2x + o * chs + base) = make_float4(xq[o][0], xq[o][1], xq[o][2], xq[o][3]);
            *(float4*)(L2c + o * chs + base) = make_float4(cq[o][0], cq[o][1], cq[o][2], cq[o][3]);
        }
    }
}

// ================= navg5p = 5x5 conv + 2x2 pool =================
// tile 64x16, stage 68x20 (stride 68, 17 groups odd)
constexpr int VTW = 64, VTH = 16, VSW = 68, VSH = 20;

__device__ __forceinline__ void stage5(const float* __restrict__ xin,
                                       const float* __restrict__ cin,
                                       float (*sc)[VSH][VSW], float (*sp)[VSH][VSW],
                                       int tid, int Y0, int X0, int H, int W,
                                       size_t bofs, size_t chs, bool interior) {
    for (int ci = 0; ci < 2; ++ci) {
        const size_t base = (size_t)ci * chs + bofs;
        if (interior) {
            // window starts at X0-2 (8B-aligned): float2 staging, b64 LDS writes
            const size_t o0 = base + (size_t)(Y0 - 2) * W + (X0 - 2);
            for (int i = tid; i < VSH * (VSW / 2); i += 256) {
                const int ly = i / (VSW / 2), k = i - ly * (VSW / 2);
                const size_t o = o0 + (size_t)ly * W + 2 * k;
                const float2 cv = *(const float2*)(cin + o);
                const float2 xv = *(const float2*)(xin + o);
                *(float2*)&sc[ci][ly][2 * k] = cv;
                *(float2*)&sp[ci][ly][2 * k] = make_float2(xv.x * cv.x, xv.y * cv.y);
            }
        } else {
            for (int i = tid; i < VSH * VSW; i += 256) {
                const int ly = i / VSW, lx = i - ly * VSW;
                const int gy = Y0 + ly - 2, gx = X0 + lx - 2;
                float cv = 0.f, pv = 0.f;
                if (gy >= 0 && gy < H && gx >= 0 && gx < W) {
                    const size_t o = base + (size_t)gy * W + gx;
                    cv = cin[o]; pv = xin[o] * cv;
                }
                sc[ci][ly][lx] = cv; sp[ci][ly][lx] = pv;
            }
        }
    }
}

__global__ __launch_bounds__(256)
void navg5p_kernel(const float* __restrict__ xin, const float* __restrict__ cin,
                   const float* __restrict__ w, const float* __restrict__ bias,
                   float* __restrict__ FAx, float* __restrict__ FAc,
                   float* __restrict__ HPx, float* __restrict__ HPc,
                   int H, int W) {
    __shared__ __align__(16) float sc[2][VSH][VSW], sp[2][VSH][VSW];   // 21760 B
    __shared__ float sinvf[2], sbf[2];

    const int tid = threadIdx.x;
    const int b = blockIdx.z;
    const int Y0 = blockIdx.y * VTH, X0 = blockIdx.x * VTW;
    const int npix = H * W;
    const size_t bofs = (size_t)b * npix;
    const size_t chs = (size_t)NB * npix;

    const bool interior = (X0 >= 2) && (X0 + VTW + 2 <= W) && (Y0 >= 2) && (Y0 + VTH + 2 <= H);

    if (tid < 2) {
        float s = 0.f;
        for (int i = 0; i < 50; ++i) s += w[tid * 50 + i];
        sinvf[tid] = 1.f / s;
        sbf[tid] = bias[tid];
    }
    stage5(xin, cin, sc, sp, tid, Y0, X0, H, W, bofs, chs, interior);
    __syncthreads();

    const int row = tid >> 4, lx4 = (tid & 15) * 4;
    f32x2 ca[4], pa[4];
    conv5x4<2>(&sc[0][row][lx4], &sp[0][row][lx4], VSH * VSW, VSW, w, ca, pa);

    const int gy = Y0 + row, gx = X0 + lx4;
    float xv[2][4], cv[2][4];
#pragma unroll
    for (int j = 0; j < 4; ++j) {
        f32x2 r = { frcp(ca[j].x + 1e-20f), frcp(ca[j].y + 1e-20f) };
        xv[0][j] = pa[j].x * r.x + sbf[0];  xv[1][j] = pa[j].y * r.y + sbf[1];
        cv[0][j] = ca[j].x * sinvf[0];      cv[1][j] = ca[j].y * sinvf[1];
    }
    if (gy < H && gx < W) {
        const size_t base = bofs + (size_t)gy * W + gx;
#pragma unroll
        for (int o = 0; o < 2; ++o) {
            *(float4*)(FAx + o * chs + base) = make_float4(xv[o][0], xv[o][1], xv[o][2], xv[o][3]);
            *(float4*)(FAc + o * chs + base) = make_float4(cv[o][0], cv[o][1], cv[o][2], cv[o][3]);
        }
    }

    // pool 2x2 (first-wins argmax of c): partner row = row^1 -> lane^16
    float pcv[2][4], pxv[2][4];
#pragma unroll
    for (int o = 0; o < 2; ++o)
#pragma unroll
        for (int j = 0; j < 4; ++j) {
            pcv[o][j] = __shfl_xor(cv[o][j], 16);
            pxv[o][j] = __shfl_xor(xv[o][j], 16);
        }
    if ((row & 1) == 0 && gy < H && gx < W) {
        const int Wh = W >> 1;
        const int np1 = (H >> 1) * Wh;
        const int hy = gy >> 1;
        const int hx0 = gx >> 1;
#pragma unroll
        for (int o = 0; o < 2; ++o) {
            float bcg[2], bxg[2];
#pragma unroll
            for (int g = 0; g < 2; ++g) {
                const float c00 = cv[o][2 * g], c01 = cv[o][2 * g + 1];
                const float c10 = pcv[o][2 * g], c11 = pcv[o][2 * g + 1];
                const float x00 = xv[o][2 * g], x01 = xv[o][2 * g + 1];
                const float x10 = pxv[o][2 * g], x11 = pxv[o][2 * g + 1];
                float bc = c00, bx = x00;
                if (c01 > bc) { bc = c01; bx = x01; }
                if (c10 > bc) { bc = c10; bx = x10; }
                if (c11 > bc) { bc = c11; bx = x11; }
                bcg[g] = bc * 0.25f; bxg[g] = bx;
            }
            const size_t ho = (size_t)o * NB * np1 + (size_t)b * np1 + (size_t)hy * Wh + hx0;
            *(float2*)(HPc + ho) = make_float2(bcg[0], bcg[1]);
            *(float2*)(HPx + ho) = make_float2(bxg[0], bxg[1]);
        }
    }
}

// ================= navg5v: 5x5 conv only (4 px/thread) =================
__global__ __launch_bounds__(256)
void navg5v_kernel(const float* __restrict__ xin, const float* __restrict__ cin,
                   const float* __restrict__ w, const float* __restrict__ bias,
                   float* __restrict__ xout, float* __restrict__ cout,
                   int H, int W) {
    __shared__ __align__(16) float sc[2][VSH][VSW], sp[2][VSH][VSW];
    __shared__ float sinvf[2];

    const int tid = threadIdx.x;
    const int b = blockIdx.z;
    const int Y0 = blockIdx.y * VTH, X0 = blockIdx.x * VTW;
    const int npix = H * W;
    const size_t bofs = (size_t)b * npix;
    const size_t chs = (size_t)NB * npix;

    const bool interior = (X0 >= 2) && (X0 + VTW + 2 <= W) && (Y0 >= 2) && (Y0 + VTH + 2 <= H);

    if (tid < 2) {
        float s = 0.f;
        for (int i = 0; i < 50; ++i) s += w[tid * 50 + i];
        sinvf[tid] = 1.f / s;
    }
    stage5(xin, cin, sc, sp, tid, Y0, X0, H, W, bofs, chs, interior);
    __syncthreads();

    const int row = tid >> 4, lx4 = (tid & 15) * 4;
    f32x2 ca[4], pa[4];
    conv5x4<2>(&sc[0][row][lx4], &sp[0][row][lx4], VSH * VSW, VSW, w, ca, pa);

    const int gy = Y0 + row, gx = X0 + lx4;
    if (gy < H && gx < W) {
        const float bb0 = bias[0], bb1 = bias[1];
        float xq[2][4], cq[2][4];
#pragma unroll
        for (int j = 0; j < 4; ++j) {
            f32x2 r = { frcp(ca[j].x + 1e-20f), frcp(ca[j].y + 1e-20f) };
            xq[0][j] = pa[j].x * r.x + bb0;  xq[1][j] = pa[j].y * r.y + bb1;
            cq[0][j] = ca[j].x * sinvf[0];   cq[1][j] = ca[j].y * sinvf[1];
        }
        const size_t off = bofs + (size_t)gy * W + gx;
#pragma unroll
        for (int o = 0; o < 2; ++o) {
            *(float4*)(xout + o * chs + off) = make_float4(xq[o][0], xq[o][1], xq[o][2], xq[o][3]);
            *(float4*)(cout + o * chs + off) = make_float4(cq[o][0], cq[o][1], cq[o][2], cq[o][3]);
        }
    }
}

// ================= sub-res 3x3 cat kernel (1 px/thread, small grids) ======
template<bool UPA, bool UPB>
__global__ __launch_bounds__(256)
void navg3_kernel(const float* __restrict__ xA, const float* __restrict__ cA,
                  const float* __restrict__ xB, const float* __restrict__ cB,
                  const float* __restrict__ w, const float* __restrict__ bias,
                  float* __restrict__ xout, float* __restrict__ cout,
                  int H, int W) {
    __shared__ float sc[4][TY + 2][TX + 2];
    __shared__ float sp[4][TY + 2][TX + 2];
    __shared__ float sinvf[2];

    const int b = blockIdx.z;
    const int npix = H * W;
    const size_t chs = (size_t)NB * npix;
    const int tid = threadIdx.y * TX + threadIdx.x;

    if (tid < 2) {
        float s = 0.f;
        for (int i = 0; i < 36; ++i) s += w[tid * 36 + i];
        sinvf[tid] = 1.f / s;
    }

    const int y0 = blockIdx.y * TY - 1;
    const int x0 = blockIdx.x * TX - 1;
    const int Ws2 = W >> 1;
    const int npixS = (H >> 1) * Ws2;

#pragma unroll
    for (int ch = 0; ch < 4; ++ch) {
        const bool up = (ch < 2) ? UPA : UPB;
        const float* xs = (ch < 2) ? xA : xB;
        const float* cs = (ch < 2) ? cA : cB;
        const int sch = ch & 1;
        const size_t base = up ? ((size_t)sch * NB * npixS + (size_t)b * npixS)
                               : ((size_t)sch * chs + (size_t)b * npix);
        for (int i = tid; i < (TY + 2) * (TX + 2); i += 256) {
            const int ly = i / (TX + 2), lx = i % (TX + 2);
            const int gy = y0 + ly, gx = x0 + lx;
            float cv = 0.f, pv = 0.f;
            if (gy >= 0 && gy < H && gx >= 0 && gx < W) {
                const size_t o = up ? (base + (size_t)(gy >> 1) * Ws2 + (gx >> 1))
                                    : (base + (size_t)gy * W + gx);
                cv = cs[o];
                pv = xs[o] * cv;
            }
            sc[ch][ly][lx] = cv;
            sp[ch][ly][lx] = pv;
        }
    }
    __syncthreads();

    const int gh = blockIdx.y * TY + threadIdx.y;
    const int gw = blockIdx.x * TX + threadIdx.x;
    if (gh < H && gw < W) {
        const size_t off = (size_t)b * npix + (size_t)gh * W + gw;
        f32x2 ca = splat2(0.f), pa = splat2(0.f);
#pragma unroll
        for (int ci = 0; ci < 4; ++ci)
#pragma unroll
            for (int kh = 0; kh < 3; ++kh)
#pragma unroll
                for (int kw = 0; kw < 3; ++kw) {
                    const int q = (ci * 3 + kh) * 3 + kw;
                    const f32x2 wv = { w[q], w[36 + q] };
                    ca += splat2(sc[ci][threadIdx.y + kh][threadIdx.x + kw]) * wv;
                    pa += splat2(sp[ci][threadIdx.y + kh][threadIdx.x + kw]) * wv;
                }
        xout[off]       = pa.x * frcp(ca.x + 1e-20f) + bias[0];
        xout[chs + off] = pa.y * frcp(ca.y + 1e-20f) + bias[1];
        cout[off]       = ca.x * sinvf[0];
        cout[chs + off] = ca.y * sinvf[1];
    }
}

// ========== vectorized 3x3 cat (4 px/thread, tile 32x32) ==========
constexpr int GTW = 32, GTH = 32, GSW = 34, GSH = 34, GSS = 36;

template<bool UPA, bool UPB>
__device__ __forceinline__ void stage3(const float* __restrict__ xA, const float* __restrict__ cA,
                                       const float* __restrict__ xB, const float* __restrict__ cB,
                                       float (*sc)[GSH][GSS], float (*sp)[GSH][GSS],
                                       int tid, int Y0, int X0, int H, int W,
                                       int b) {
    const int npix = H * W;
    const size_t chs = (size_t)NB * npix;
    const int Ws2 = W >> 1;
    const int npixS = (H >> 1) * Ws2;
#pragma unroll
    for (int ch = 0; ch < 4; ++ch) {
        const bool up = (ch < 2) ? UPA : UPB;
        const float* xs = (ch < 2) ? xA : xB;
        const float* cs = (ch < 2) ? cA : cB;
        const int sch = ch & 1;
        const size_t base = up ? ((size_t)sch * NB * npixS + (size_t)b * npixS)
                               : ((size_t)sch * chs + (size_t)b * npix);
        for (int i = tid; i < GSH * GSW; i += 256) {
            const int ly = i / GSW, lx = i - ly * GSW;
            const int gy = Y0 + ly - 1, gx = X0 + lx - 1;
            float cv = 0.f, pv = 0.f;
            if (gy >= 0 && gy < H && gx >= 0 && gx < W) {
                const size_t o = up ? (base + (size_t)(gy >> 1) * Ws2 + (gx >> 1))
                                    : (base + (size_t)gy * W + gx);
                cv = cs[o]; pv = xs[o] * cv;
            }
            sc[ch][ly][lx] = cv; sp[ch][ly][lx] = pv;
        }
    }
}

template<bool UPA, bool UPB>
__global__ __launch_bounds__(256)
void navg3v_kernel(const float* __restrict__ xA, const float* __restrict__ cA,
                   const float* __restrict__ xB, const float* __restrict__ cB,
                   const float* __restrict__ w, const float* __restrict__ bias,
                   float* __restrict__ xout, float* __restrict__ cout,
                   int H, int W) {
    __shared__ __align__(16) float sc[4][GSH][GSS], sp[4][GSH][GSS];   // 39168 B
    __shared__ float sinvf[2];

    const int tid = threadIdx.x;
    const int b = blockIdx.z;
    const int Y0 = blockIdx.y * GTH, X0 = blockIdx.x * GTW;
    const int npix = H * W;
    const size_t bofs = (size_t)b * npix;
    const size_t chs = (size_t)NB * npix;

    if (tid < 2) {
        float s = 0.f;
        for (int i = 0; i < 36; ++i) s += w[tid * 36 + i];
        sinvf[tid] = 1.f / s;
    }
    stage3<UPA, UPB>(xA, cA, xB, cB, sc, sp, tid, Y0, X0, H, W, b);
    __syncthreads();

    const int row = tid >> 3, lx4 = (tid & 7) * 4;
    f32x2 ca[4], pa[4];
    conv3x4<4>(&sc[0][row][lx4], &sp[0][row][lx4], GSH * GSS, GSS, w, ca, pa);

    const int gy = Y0 + row, gx = X0 + lx4;
    if (gy < H && gx < W) {
        const float bb0 = bias[0], bb1 = bias[1];
        float xq[2][4], cq[2][4];
#pragma unroll
        for (int j = 0; j < 4; ++j) {
            xq[0][j] = pa[j].x * frcp(ca[j].x + 1e-20f) + bb0;
            xq[1][j] = pa[j].y * frcp(ca[j].y + 1e-20f) + bb1;
            cq[0][j] = ca[j].x * sinvf[0];
            cq[1][j] = ca[j].y * sinvf[1];
        }
        const size_t off = bofs + (size_t)gy * W + gx;
#pragma unroll
        for (int o = 0; o < 2; ++o) {
            *(float4*)(xout + o * chs + off) = make_float4(xq[o][0], xq[o][1], xq[o][2], xq[o][3]);
            *(float4*)(cout + o * chs + off) = make_float4(cq[o][0], cq[o][1], cq[o][2], cq[o][3]);
        }
    }
}

// ===== final fused layer: cat(up2(HA), FA) -> 3x3 -> 1x1 =====
__global__ __launch_bounds__(256)
void navg3f_kernel(const float* __restrict__ xA, const float* __restrict__ cA,
                   const float* __restrict__ xB, const float* __restrict__ cB,
                   const float* __restrict__ w, const float* __restrict__ bias,
                   const float* __restrict__ w4, const float* __restrict__ b4,
                   float* __restrict__ xout, float* __restrict__ cout,
                   int H, int W) {
    __shared__ __align__(16) float sc[4][GSH][GSS], sp[4][GSH][GSS];
    __shared__ float sinvf[2];

    const int tid = threadIdx.x;
    const int b = blockIdx.z;
    const int Y0 = blockIdx.y * GTH, X0 = blockIdx.x * GTW;
    const int npix = H * W;
    const size_t bofs = (size_t)b * npix;

    if (tid < 2) {
        float s = 0.f;
        for (int i = 0; i < 36; ++i) s += w[tid * 36 + i];
        sinvf[tid] = 1.f / s;
    }
    stage3<true, false>(xA, cA, xB, cB, sc, sp, tid, Y0, X0, H, W, b);
    __syncthreads();

    const int row = tid >> 3, lx4 = (tid & 7) * 4;
    f32x2 ca[4], pa[4];
    conv3x4<4>(&sc[0][row][lx4], &sp[0][row][lx4], GSH * GSS, GSS, w, ca, pa);

    const float w40 = w4[0], w41 = w4[1], b40 = b4[0];
    const float inv4 = frcp(w40 + w41);
    const float bb0 = bias[0], bb1 = bias[1];
    float xq[4], cq[4];
#pragma unroll
    for (int j = 0; j < 4; ++j) {
        const float xv0 = pa[j].x * frcp(ca[j].x + 1e-20f) + bb0;
        const float xv1 = pa[j].y * frcp(ca[j].y + 1e-20f) + bb1;
        const float cv0 = ca[j].x * sinvf[0];
        const float cv1 = ca[j].y * sinvf[1];
        const float ca4 = w40 * cv0 + w41 * cv1;
        xq[j] = (w40 * xv0 * cv0 + w41 * xv1 * cv1) * frcp(ca4 + 1e-20f) + b40;
        cq[j] = ca4 * inv4;
    }
    const size_t off = bofs + (size_t)(Y0 + row) * W + (X0 + lx4);
    *(float4*)(xout + off) = make_float4(xq[0], xq[1], xq[2], xq[3]);
    *(float4*)(cout + off) = make_float4(cq[0], cq[1], cq[2], cq[3]);
}

// ================= FALLBACK: fused full-res encoder =================
constexpr int FTW = 32, FTH = 16;
constexpr int FSW = 44, FSH = 28;
constexpr int FAW = 40, FAH = 24;
constexpr int FAS = 44;
constexpr int FBW = 36, FBH = 20;

union EncSmem {
    struct { float c[FSH][FSW]; float p[FSH][FSW]; } s0;
    struct { float c[2][FBH][FBW]; float p[2][FBH][FBW]; } s2;
};

__global__ __launch_bounds__(256)
void enc_full_kernel(const float* __restrict__ x0, const float* __restrict__ c0,
                     const float* __restrict__ w1, const float* __restrict__ b1,
                     const float* __restrict__ w2, const float* __restrict__ b2,
                     const float* __restrict__ w3, const float* __restrict__ b3,
                     float* __restrict__ FAx, float* __restrict__ FAc,
                     float* __restrict__ HPx, float* __restrict__ HPc,
                     int H, int W) {
    __shared__ __align__(16) EncSmem u;
    __shared__ __align__(16) float s1c[2][FAH][FAS], s1p[2][FAH][FAS];
    __shared__ float sinvf[6], sbf[6];

    const int tid = threadIdx.x;
    const int b = blockIdx.z;
    const int Y0 = blockIdx.y * FTH, X0 = blockIdx.x * FTW;
    const int npix = H * W;
    const size_t bofs = (size_t)b * npix;
    const size_t chs = (size_t)NB * npix;

    const bool interior = (X0 >= 6) && (X0 + FTW + 6 <= W) && (Y0 >= 6) && (Y0 + FTH + 6 <= H);

    if (tid < 6) {
        const int L = tid >> 1, o = tid & 1;
        const float* wl = (L == 0) ? w1 : (L == 1) ? w2 : w3;
        const float* bl = (L == 0) ? b1 : (L == 1) ? b2 : b3;
        const int n = (L == 0) ? 25 : 50;
        float s = 0.f;
        for (int i = 0; i < n; ++i) s += wl[o * n + i];
        sinvf[tid] = 1.f / s;
        sbf[tid] = bl[o];
    }

    if (interior) {
        const size_t o0 = bofs + (size_t)(Y0 - 6) * W + (X0 - 6);
        for (int i = tid; i < FSH * FSW; i += 256) {
            const int ly = i / FSW, lx = i - ly * FSW;
            const size_t o = o0 + (size_t)ly * W + lx;
            const float cv = c0[o];
            u.s0.c[ly][lx] = cv; u.s0.p[ly][lx] = x0[o] * cv;
        }
    } else {
        for (int i = tid; i < FSH * FSW; i += 256) {
            const int ly = i / FSW, lx = i - ly * FSW;
            const int gy = Y0 + ly - 6, gx = X0 + lx - 6;
            float cv = 0.f, pv = 0.f;
            if (gy >= 0 && gy < H && gx >= 0 && gx < W) {
                const size_t o = bofs + (size_t)gy * W + gx;
                cv = c0[o]; pv = x0[o] * cv;
            }
            u.s0.c[ly][lx] = cv; u.s0.p[ly][lx] = pv;
        }
    }
    __syncthreads();

    if (tid < FAH * (FAW / 4)) {
        const int row = tid / (FAW / 4), lx = (tid % (FAW / 4)) * 4;
        f32x2 ca[4], pa[4];
        conv5x4<1>(&u.s0.c[row][lx], &u.s0.p[row][lx], 0, FSW, w1, ca, pa);
        const f32x2 iv = { sinvf[0], sinvf[1] };
        const f32x2 bb = { sbf[0], sbf[1] };
        float cq[2][4], pq[2][4];
        if (interior) {
#pragma unroll
            for (int j = 0; j < 4; ++j) {
                f32x2 r = { frcp(ca[j].x + 1e-20f), frcp(ca[j].y + 1e-20f) };
                const f32x2 xv = pa[j] * r + bb;
                const f32x2 cvv = ca[j] * iv;
                cq[0][j] = cvv.x;            cq[1][j] = cvv.y;
                pq[0][j] = xv.x * cvv.x;     pq[1][j] = xv.y * cvv.y;
            }
        } else {
            const int gy = Y0 + row - 4;
#pragma unroll
            for (int j = 0; j < 4; ++j) {
                const int gx = X0 + lx + j - 4;
                const bool in = (gy >= 0 && gy < H && gx >= 0 && gx < W);
                f32x2 r = { frcp(ca[j].x + 1e-20f), frcp(ca[j].y + 1e-20f) };
                const f32x2 xv = pa[j] * r + bb;
                const f32x2 cvv = ca[j] * iv;
                cq[0][j] = in ? cvv.x : 0.f;            cq[1][j] = in ? cvv.y : 0.f;
                pq[0][j] = in ? xv.x * cvv.x : 0.f;     pq[1][j] = in ? xv.y * cvv.y : 0.f;
            }
        }
#pragma unroll
        for (int o = 0; o < 2; ++o) {
            *(float4*)&s1c[o][row][lx] = make_float4(cq[o][0], cq[o][1], cq[o][2], cq[o][3]);
            *(float4*)&s1p[o][row][lx] = make_float4(pq[o][0], pq[o][1], pq[o][2], pq[o][3]);
        }
    }
    __syncthreads();

    if (tid < FBH * (FBW / 4)) {
        const int row = tid / (FBW / 4), lx = (tid % (FBW / 4)) * 4;
        f32x2 ca[4], pa[4];
        conv5x4<2>(&s1c[0][row][lx], &s1p[0][row][lx], FAH * FAS, FAS, w2, ca, pa);
        const f32x2 iv = { sinvf[2], sinvf[3] };
        const f32x2 bb = { sbf[2], sbf[3] };
        float cq[2][4], pq[2][4];
        if (interior) {
#pragma unroll
            for (int j = 0; j < 4; ++j) {
                f32x2 r = { frcp(ca[j].x + 1e-20f), frcp(ca[j].y + 1e-20f) };
                const f32x2 xv = pa[j] * r + bb;
                const f32x2 cvv = ca[j] * iv;
                cq[0][j] = cvv.x;            cq[1][j] = cvv.y;
                pq[0][j] = xv.x * cvv.x;     pq[1][j] = xv.y * cvv.y;
            }
        } else {
            const int gy = Y0 + row - 2;
#pragma unroll
            for (int j = 0; j < 4; ++j) {
                const int gx = X0 + lx + j - 2;
                const bool in = (gy >= 0 && gy < H && gx >= 0 && gx < W);
                f32x2 r = { frcp(ca[j].x + 1e-20f), frcp(ca[j].y + 1e-20f) };
                const f32x2 xv = pa[j] * r + bb;
                const f32x2 cvv = ca[j] * iv;
                cq[0][j] = in ? cvv.x : 0.f;            cq[1][j] = in ? cvv.y : 0.f;
                pq[0][j] = in ? xv.x * cvv.x : 0.f;     pq[1][j] = in ? xv.y * cvv.y : 0.f;
            }
        }
#pragma unroll
        for (int o = 0; o < 2; ++o) {
            *(float4*)&u.s2.c[o][row][lx] = make_float4(cq[o][0], cq[o][1], cq[o][2], cq[o][3]);
            *(float4*)&u.s2.p[o][row][lx] = make_float4(pq[o][0], pq[o][1], pq[o][2], pq[o][3]);
        }
    }
    __syncthreads();

    if (tid < FTH * (FTW / 4)) {
        const int row = tid / (FTW / 4), lx = (tid % (FTW / 4)) * 4;
        f32x2 ca[4], pa[4];
        conv5x4<2>(&u.s2.c[0][row][lx], &u.s2.p[0][row][lx], FBH * FBW, FBW, w3, ca, pa);
        const f32x2 iv = { sinvf[4], sinvf[5] };
        const f32x2 bb = { sbf[4], sbf[5] };
        float xv[2][4], cv[2][4];
#pragma unroll
        for (int j = 0; j < 4; ++j) {
            f32x2 r = { frcp(ca[j].x + 1e-20f), frcp(ca[j].y + 1e-20f) };
            const f32x2 x2 = pa[j] * r + bb;
            const f32x2 c2 = ca[j] * iv;
            xv[0][j] = x2.x; xv[1][j] = x2.y;
            cv[0][j] = c2.x; cv[1][j] = c2.y;
        }
        const int gy = Y0 + row;
        const size_t base = bofs + (size_t)gy * W + (X0 + lx);
#pragma unroll
        for (int o = 0; o < 2; ++o) {
            *(float4*)(FAx + o * chs + base) = make_float4(xv[o][0], xv[o][1], xv[o][2], xv[o][3]);
            *(float4*)(FAc + o * chs + base) = make_float4(cv[o][0], cv[o][1], cv[o][2], cv[o][3]);
        }
        float pcv[2][4], pxv[2][4];
#pragma unroll
        for (int o = 0; o < 2; ++o)
#pragma unroll
            for (int j = 0; j < 4; ++j) {
                pcv[o][j] = __shfl_xor(cv[o][j], 8);
                pxv[o][j] = __shfl_xor(xv[o][j], 8);
            }
        if ((row & 1) == 0) {
            const int Wh = W >> 1;
            const int np1 = (H >> 1) * Wh;
            const int hy = (Y0 + row) >> 1;
            const int hx0 = (X0 + lx) >> 1;
#pragma unroll
            for (int o = 0; o < 2; ++o)
#pragma unroll
                for (int g = 0; g < 2; ++g) {
                    const float c00 = cv[o][2 * g], c01 = cv[o][2 * g + 1];
                    const float c10 = pcv[o][2 * g], c11 = pcv[o][2 * g + 1];
                    const float x00 = xv[o][2 * g], x01 = xv[o][2 * g + 1];
                    const float x10 = pxv[o][2 * g], x11 = pxv[o][2 * g + 1];
                    float bc = c00, bx = x00;
                    if (c01 > bc) { bc = c01; bx = x01; }
                    if (c10 > bc) { bc = c10; bx = x10; }
                    if (c11 > bc) { bc = c11; bx = x11; }
                    const size_t ho = (size_t)o * NB * np1 + (size_t)b * np1 + (size_t)hy * Wh + hx0 + g;
                    HPc[ho] = bc * 0.25f;
                    HPx[ho] = bx;
                }
        }
    }
}

extern "C" void kernel_launch(void* const* d_in, const int* in_sizes, int n_in,
                              void* d_out, int out_size, void* d_ws, size_t ws_size,
                              hipStream_t stream) {
    const float* x0  = (const float*)d_in[0];
    const float* c0  = (const float*)d_in[1];
    const float* w1  = (const float*)d_in[2];
    const float* w2  = (const float*)d_in[3];
    const float* w3  = (const float*)d_in[4];
    const float* w4  = (const float*)d_in[5];
    const float* w34 = (const float*)d_in[6];
    const float* w23 = (const float*)d_in[7];
    const float* w12 = (const float*)d_in[8];
    const float* b1  = (const float*)d_in[9];
    const float* b2  = (const float*)d_in[10];
    const float* b3  = (const float*)d_in[11];
    const float* b4  = (const float*)d_in[12];
    const float* b34 = (const float*)d_in[13];
    const float* b23 = (const float*)d_in[14];
    const float* b12 = (const float*)d_in[15];

    float* out = (float*)d_out;   // fp32: xout plane then cout plane

    const int H0 = 512, W0 = 640, H1 = 256, W1 = 320, H2 = 128, W2 = 160, H3 = 64, W3 = 80;
    const size_t n0 = (size_t)NB * H0 * W0;
    const size_t n1 = n0 / 4, n2 = n0 / 16, n3 = n0 / 64;

    const size_t arena = 8 * n1 + 8 * n2 + 8 * n3;
    const bool split_enc = ws_size >= (8 * n0 + arena) * sizeof(float);

    float* ws = (float*)d_ws;
    float* FAx = ws;            // x1 (2ch) -- persists to the end
    float* FAc = ws + 2 * n0;   // c1 (2ch)
    float* L2x = nullptr;
    float* L2c = nullptr;
    float* sub;
    if (split_enc) {
        L2x = ws + 4 * n0;
        L2c = ws + 6 * n0;
        sub = ws + 8 * n0;
    } else {
        sub = ws + 4 * n0;
    }
    float* HPx = sub;               sub += 2 * n1;
    float* HPc = sub;               sub += 2 * n1;
    float* HAx = sub;               sub += 2 * n1;
    float* HAc = sub;               sub += 2 * n1;
    float* QPx = sub;               sub += 2 * n2;
    float* QPc = sub;               sub += 2 * n2;
    float* QAx = sub;               sub += 2 * n2;
    float* QAc = sub;               sub += 2 * n2;
    float* EPx = sub;               sub += 2 * n3;
    float* EPc = sub;               sub += 2 * n3;
    float* EAx = sub;               sub += 2 * n3;
    float* EAc = sub;               sub += 2 * n3;

    dim3 blk(TX, TY);
    auto gdim  = [](int W, int H) { return dim3((W + TX - 1) / TX, (H + TY - 1) / TY, NB); };
    auto gdim5 = [](int W, int H) { return dim3((W + VTW - 1) / VTW, (H + VTH - 1) / VTH, NB); };
    auto gdim3v = [](int W, int H) { return dim3((W + GTW - 1) / GTW, (H + GTH - 1) / GTH, NB); };

    if (split_enc) {
        enc12_kernel<<<dim3(W0 / ATW, H0 / ATH, NB), 256, 0, stream>>>(
            x0, c0, w1, b1, w2, b2, L2x, L2c, H0, W0);
        navg5p_kernel<<<gdim5(W0, H0), 256, 0, stream>>>(
            L2x, L2c, w3, b3, FAx, FAc, HPx, HPc, H0, W0);
    } else {
        enc_full_kernel<<<dim3(W0 / FTW, H0 / FTH, NB), 256, 0, stream>>>(
            x0, c0, w1, b1, w2, b2, w3, b3, FAx, FAc, HPx, HPc, H0, W0);
    }

    // L5: HP -> HA (w2,b2)
    navg5v_kernel<<<gdim5(W1, H1), 256, 0, stream>>>(HPx, HPc, w2, b2, HAx, HAc, H1, W1);
    // L6 + pool fused: HA -> HP (x2_ds,c2_ds) + QP (pooled quarter)
    navg5p_kernel<<<gdim5(W1, H1), 256, 0, stream>>>(HAx, HAc, w3, b3, HPx, HPc, QPx, QPc, H1, W1);
    // L8 + pool fused: QP -> QA (x3_ds,c3_ds) + EP (pooled eighth)
    navg5p_kernel<<<gdim5(W2, H2), 256, 0, stream>>>(QPx, QPc, w2, b2, QAx, QAc, EPx, EPc, H2, W2);
    // L10: EP -> EA (w2,b2)  [EA := x4_ds,c4_ds]
    navg5v_kernel<<<gdim5(W3, H3), 256, 0, stream>>>(EPx, EPc, w2, b2, EAx, EAc, H3, W3);
    // L12: cat(QA, up2(EA)) -> QP (w34,b34)
    navg3_kernel<false, true><<<gdim(W2, H2), blk, 0, stream>>>(
        QAx, QAc, EAx, EAc, w34, b34, QPx, QPc, H2, W2);
    // L14: cat(HP, up2(QP)) -> HA (w23,b23)  [vectorized]
    navg3v_kernel<false, true><<<gdim3v(W1, H1), 256, 0, stream>>>(
        HPx, HPc, QPx, QPc, w23, b23, HAx, HAc, H1, W1);
    // L16 + L17 fused: cat(up2(HA), FA) -> full res, then 1x1 w4, fp32 out
    navg3f_kernel<<<gdim3v(W0, H0), 256, 0, stream>>>(
        HAx, HAc, FAx, FAc, w12, b12, w4, b4, out, out + n0, H0, W0);
}

// Round 6
// 366.028 us; speedup vs baseline: 1.1746x; 1.1060x over previous
//
#include <hip/hip_runtime.h>

// PretrainedCNN: normalized-convolution U-Net, B=16, 512x640, NC=2.
// Inputs fp32; OUTPUT d_out fp32: xout plane (n0) then cout plane (n0).
// Intermediates fp32 planar [ch][b][h][w], plane stride NB*npix.
// Round 14: (1) enc_h1 = L5+L6+pool fused at H1 (HA round-trip ~42MB and one
// launch removed; 51KB LDS, 3 blocks/CU). (2) XCD-aware bijective block
// swizzle on all big kernels (consecutive blocks -> same XCD-L2 chunk;
// enc12 FETCH was 2.1x input from cross-XCD halo re-reads). (3) dead
// pool_kernel removed; HP/HA buffer roles swapped downstream of enc_h1.

#define NB 16

typedef __attribute__((ext_vector_type(2))) float f32x2;

__device__ __forceinline__ f32x2 splat2(float s) { f32x2 v = {s, s}; return v; }
__device__ __forceinline__ float frcp(float x) { return __builtin_amdgcn_rcpf(x); }

// XCD-aware swizzle: physical dispatch order round-robins XCDs; remap so each
// XCD owns a contiguous (spatially local) chunk of the grid. Bijective when
// n%8==0 (always true here: gridDim.z=16).
__device__ __forceinline__ void swz_bid(int& bx, int& by, int& bz) {
    const int gx = (int)gridDim.x, gy = (int)gridDim.y, gz = (int)gridDim.z;
    const int n = gx * gy * gz;
    int lin = (int)blockIdx.x + gx * ((int)blockIdx.y + gy * (int)blockIdx.z);
    if ((n & 7) == 0) lin = (lin & 7) * (n >> 3) + (lin >> 3);
    const int pl = gx * gy;
    bz = lin / pl; const int r = lin - bz * pl;
    by = r / gx; bx = r - by * gx;
}

constexpr int TX = 32, TY = 8;

// ---- shared conv helpers (compact, v_pk_fma_f32 channel-packed) ----
template<int CIN>
__device__ __forceinline__ void conv5x4(const float* sc, const float* sp,
                                        int chStride, int rw,
                                        const float* __restrict__ w,
                                        f32x2 ca[4], f32x2 pa[4]) {
#pragma unroll
    for (int j = 0; j < 4; ++j) { ca[j] = splat2(0.f); pa[j] = splat2(0.f); }
#pragma unroll
    for (int ci = 0; ci < CIN; ++ci) {
#pragma unroll
        for (int kh = 0; kh < 5; ++kh) {
            const float* rc = sc + ci * chStride + kh * rw;
            const float* rp = sp + ci * chStride + kh * rw;
            float cw[8], pw[8];
            *(float4*)&cw[0] = *(const float4*)rc;
            *(float4*)&cw[4] = *(const float4*)(rc + 4);
            *(float4*)&pw[0] = *(const float4*)rp;
            *(float4*)&pw[4] = *(const float4*)(rp + 4);
#pragma unroll
            for (int kw = 0; kw < 5; ++kw) {
                const int q = (ci * 5 + kh) * 5 + kw;
                const f32x2 wv = { w[q], w[CIN * 25 + q] };
#pragma unroll
                for (int j = 0; j < 4; ++j) {
                    ca[j] += splat2(cw[j + kw]) * wv;   // v_pk_fma_f32
                    pa[j] += splat2(pw[j + kw]) * wv;
                }
            }
        }
    }
}

template<int CIN>
__device__ __forceinline__ void conv3x4(const float* sc, const float* sp,
                                        int chStride, int rw,
                                        const float* __restrict__ w,
                                        f32x2 ca[4], f32x2 pa[4]) {
#pragma unroll
    for (int j = 0; j < 4; ++j) { ca[j] = splat2(0.f); pa[j] = splat2(0.f); }
#pragma unroll
    for (int ci = 0; ci < CIN; ++ci) {
#pragma unroll
        for (int kh = 0; kh < 3; ++kh) {
            const float* rc = sc + ci * chStride + kh * rw;
            const float* rp = sp + ci * chStride + kh * rw;
            float cw[6], pw[6];
            *(float4*)&cw[0] = *(const float4*)rc;
            *(float2*)&cw[4] = *(const float2*)(rc + 4);
            *(float4*)&pw[0] = *(const float4*)rp;
            *(float2*)&pw[4] = *(const float2*)(rp + 4);
#pragma unroll
            for (int kw = 0; kw < 3; ++kw) {
                const int q = (ci * 3 + kh) * 3 + kw;
                const f32x2 wv = { w[q], w[CIN * 9 + q] };
#pragma unroll
                for (int j = 0; j < 4; ++j) {
                    ca[j] += splat2(cw[j + kw]) * wv;
                    pa[j] += splat2(pw[j + kw]) * wv;
                }
            }
        }
    }
}

// ================= enc12 = L1+L2 fused (halo 4) =================
constexpr int ATW = 32, ATH = 16;
constexpr int ASW = 40, ASH = 24, ASS = 44;
constexpr int AAW = 36, AAH = 20, AAS = 36;

__global__ __launch_bounds__(256)
void enc12_kernel(const float* __restrict__ x0, const float* __restrict__ c0,
                  const float* __restrict__ w1, const float* __restrict__ b1,
                  const float* __restrict__ w2, const float* __restrict__ b2,
                  float* __restrict__ L2x, float* __restrict__ L2c,
                  int H, int W) {
    __shared__ __align__(16) float s0c[ASH][ASS], s0p[ASH][ASS];            // 8448 B
    __shared__ __align__(16) float s1c[2][AAH][AAS], s1p[2][AAH][AAS];      // 11520 B
    __shared__ float sinvf[4], sbf[4];

    int bxi, byi, b; swz_bid(bxi, byi, b);
    const int tid = threadIdx.x;
    const int Y0 = byi * ATH, X0 = bxi * ATW;
    const int npix = H * W;
    const size_t bofs = (size_t)b * npix;
    const size_t chs = (size_t)NB * npix;

    const bool interior = (X0 >= 4) && (X0 + ATW + 4 <= W) && (Y0 >= 4) && (Y0 + ATH + 4 <= H);

    if (tid < 4) {
        const int L = tid >> 1, o = tid & 1;
        const float* wl = (L == 0) ? w1 : w2;
        const float* bl = (L == 0) ? b1 : b2;
        const int n = (L == 0) ? 25 : 50;
        float s = 0.f;
        for (int i = 0; i < n; ++i) s += wl[o * n + i];
        sinvf[tid] = 1.f / s;
        sbf[tid] = bl[o];
    }

    // stage 40x24 (halo 4)
    if (interior) {
        if (tid < ASH * (ASW / 4)) {       // 240 threads, 1 iteration
            const int row = tid / (ASW / 4), c4 = tid - row * (ASW / 4);
            const size_t o = bofs + (size_t)(Y0 - 4 + row) * W + (X0 - 4) + c4 * 4;
            const float4 cv = *(const float4*)(c0 + o);
            const float4 xv = *(const float4*)(x0 + o);
            *(float4*)&s0c[row][c4 * 4] = cv;
            *(float4*)&s0p[row][c4 * 4] = make_float4(xv.x * cv.x, xv.y * cv.y,
                                                      xv.z * cv.z, xv.w * cv.w);
        }
    } else {
        for (int i = tid; i < ASH * ASW; i += 256) {
            const int ly = i / ASW, lx = i - ly * ASW;
            const int gy = Y0 + ly - 4, gx = X0 + lx - 4;
            float cv = 0.f, pv = 0.f;
            if (gy >= 0 && gy < H && gx >= 0 && gx < W) {
                const size_t o = bofs + (size_t)gy * W + gx;
                cv = c0[o]; pv = x0[o] * cv;
            }
            s0c[ly][lx] = cv; s0p[ly][lx] = pv;
        }
    }
    __syncthreads();

    // L1: 36x20, CIN=1 -> s1
    if (tid < AAH * (AAW / 4)) {                  // 180 threads
        const int row = tid / (AAW / 4), lx = (tid % (AAW / 4)) * 4;
        f32x2 ca[4], pa[4];
        conv5x4<1>(&s0c[row][lx], &s0p[row][lx], 0, ASS, w1, ca, pa);
        const f32x2 iv = { sinvf[0], sinvf[1] };
        const f32x2 bb = { sbf[0], sbf[1] };
        float cq[2][4], pq[2][4];
        if (interior) {
#pragma unroll
            for (int j = 0; j < 4; ++j) {
                f32x2 r = { frcp(ca[j].x + 1e-20f), frcp(ca[j].y + 1e-20f) };
                const f32x2 xv = pa[j] * r + bb;
                const f32x2 cvv = ca[j] * iv;
                cq[0][j] = cvv.x;            cq[1][j] = cvv.y;
                pq[0][j] = xv.x * cvv.x;     pq[1][j] = xv.y * cvv.y;
            }
        } else {
            const int gy = Y0 + row - 2;
#pragma unroll
            for (int j = 0; j < 4; ++j) {
                const int gx = X0 + lx + j - 2;
                const bool in = (gy >= 0 && gy < H && gx >= 0 && gx < W);
                f32x2 r = { frcp(ca[j].x + 1e-20f), frcp(ca[j].y + 1e-20f) };
                const f32x2 xv = pa[j] * r + bb;
                const f32x2 cvv = ca[j] * iv;
                cq[0][j] = in ? cvv.x : 0.f;            cq[1][j] = in ? cvv.y : 0.f;
                pq[0][j] = in ? xv.x * cvv.x : 0.f;     pq[1][j] = in ? xv.y * cvv.y : 0.f;
            }
        }
#pragma unroll
        for (int o = 0; o < 2; ++o) {
            *(float4*)&s1c[o][row][lx] = make_float4(cq[o][0], cq[o][1], cq[o][2], cq[o][3]);
            *(float4*)&s1p[o][row][lx] = make_float4(pq[o][0], pq[o][1], pq[o][2], pq[o][3]);
        }
    }
    __syncthreads();

    // L2: 32x16, CIN=2 -> global (exact tiling at full res)
    if (tid < ATH * (ATW / 4)) {                  // 128 threads
        const int row = tid >> 3, lx = (tid & 7) * 4;
        f32x2 ca[4], pa[4];
        conv5x4<2>(&s1c[0][row][lx], &s1p[0][row][lx], AAH * AAS, AAS, w2, ca, pa);
        const f32x2 iv = { sinvf[2], sinvf[3] };
        const f32x2 bb = { sbf[2], sbf[3] };
        float xq[2][4], cq[2][4];
#pragma unroll
        for (int j = 0; j < 4; ++j) {
            f32x2 r = { frcp(ca[j].x + 1e-20f), frcp(ca[j].y + 1e-20f) };
            const f32x2 xv = pa[j] * r + bb;
            const f32x2 cvv = ca[j] * iv;
            xq[0][j] = xv.x;  xq[1][j] = xv.y;
            cq[0][j] = cvv.x; cq[1][j] = cvv.y;
        }
        const size_t base = bofs + (size_t)(Y0 + row) * W + (X0 + lx);
#pragma unroll
        for (int o = 0; o < 2; ++o) {
            *(float4*)(L2x + o * chs + base) = make_float4(xq[o][0], xq[o][1], xq[o][2], xq[o][3]);
            *(float4*)(L2c + o * chs + base) = make_float4(cq[o][0], cq[o][1], cq[o][2], cq[o][3]);
        }
    }
}

// ================= navg5p = 5x5 conv + 2x2 pool =================
constexpr int VTW = 64, VTH = 16, VSW = 68, VSH = 20;

__device__ __forceinline__ void stage5(const float* __restrict__ xin,
                                       const float* __restrict__ cin,
                                       float (*sc)[VSH][VSW], float (*sp)[VSH][VSW],
                                       int tid, int Y0, int X0, int H, int W,
                                       size_t bofs, size_t chs, bool interior) {
    for (int ci = 0; ci < 2; ++ci) {
        const size_t base = (size_t)ci * chs + bofs;
        if (interior) {
            const size_t o0 = base + (size_t)(Y0 - 2) * W + (X0 - 2);
            for (int i = tid; i < VSH * (VSW / 2); i += 256) {
                const int ly = i / (VSW / 2), k = i - ly * (VSW / 2);
                const size_t o = o0 + (size_t)ly * W + 2 * k;
                const float2 cv = *(const float2*)(cin + o);
                const float2 xv = *(const float2*)(xin + o);
                *(float2*)&sc[ci][ly][2 * k] = cv;
                *(float2*)&sp[ci][ly][2 * k] = make_float2(xv.x * cv.x, xv.y * cv.y);
            }
        } else {
            for (int i = tid; i < VSH * VSW; i += 256) {
                const int ly = i / VSW, lx = i - ly * VSW;
                const int gy = Y0 + ly - 2, gx = X0 + lx - 2;
                float cv = 0.f, pv = 0.f;
                if (gy >= 0 && gy < H && gx >= 0 && gx < W) {
                    const size_t o = base + (size_t)gy * W + gx;
                    cv = cin[o]; pv = xin[o] * cv;
                }
                sc[ci][ly][lx] = cv; sp[ci][ly][lx] = pv;
            }
        }
    }
}

__global__ __launch_bounds__(256)
void navg5p_kernel(const float* __restrict__ xin, const float* __restrict__ cin,
                   const float* __restrict__ w, const float* __restrict__ bias,
                   float* __restrict__ FAx, float* __restrict__ FAc,
                   float* __restrict__ HPx, float* __restrict__ HPc,
                   int H, int W) {
    __shared__ __align__(16) float sc[2][VSH][VSW], sp[2][VSH][VSW];   // 21760 B
    __shared__ float sinvf[2], sbf[2];

    int bxi, byi, b; swz_bid(bxi, byi, b);
    const int tid = threadIdx.x;
    const int Y0 = byi * VTH, X0 = bxi * VTW;
    const int npix = H * W;
    const size_t bofs = (size_t)b * npix;
    const size_t chs = (size_t)NB * npix;

    const bool interior = (X0 >= 2) && (X0 + VTW + 2 <= W) && (Y0 >= 2) && (Y0 + VTH + 2 <= H);

    if (tid < 2) {
        float s = 0.f;
        for (int i = 0; i < 50; ++i) s += w[tid * 50 + i];
        sinvf[tid] = 1.f / s;
        sbf[tid] = bias[tid];
    }
    stage5(xin, cin, sc, sp, tid, Y0, X0, H, W, bofs, chs, interior);
    __syncthreads();

    const int row = tid >> 4, lx4 = (tid & 15) * 4;
    f32x2 ca[4], pa[4];
    conv5x4<2>(&sc[0][row][lx4], &sp[0][row][lx4], VSH * VSW, VSW, w, ca, pa);

    const int gy = Y0 + row, gx = X0 + lx4;
    float xv[2][4], cv[2][4];
#pragma unroll
    for (int j = 0; j < 4; ++j) {
        f32x2 r = { frcp(ca[j].x + 1e-20f), frcp(ca[j].y + 1e-20f) };
        xv[0][j] = pa[j].x * r.x + sbf[0];  xv[1][j] = pa[j].y * r.y + sbf[1];
        cv[0][j] = ca[j].x * sinvf[0];      cv[1][j] = ca[j].y * sinvf[1];
    }
    if (gy < H && gx < W) {
        const size_t base = bofs + (size_t)gy * W + gx;
#pragma unroll
        for (int o = 0; o < 2; ++o) {
            *(float4*)(FAx + o * chs + base) = make_float4(xv[o][0], xv[o][1], xv[o][2], xv[o][3]);
            *(float4*)(FAc + o * chs + base) = make_float4(cv[o][0], cv[o][1], cv[o][2], cv[o][3]);
        }
    }

    float pcv[2][4], pxv[2][4];
#pragma unroll
    for (int o = 0; o < 2; ++o)
#pragma unroll
        for (int j = 0; j < 4; ++j) {
            pcv[o][j] = __shfl_xor(cv[o][j], 16);
            pxv[o][j] = __shfl_xor(xv[o][j], 16);
        }
    if ((row & 1) == 0 && gy < H && gx < W) {
        const int Wh = W >> 1;
        const int np1 = (H >> 1) * Wh;
        const int hy = gy >> 1;
        const int hx0 = gx >> 1;
#pragma unroll
        for (int o = 0; o < 2; ++o) {
            float bcg[2], bxg[2];
#pragma unroll
            for (int g = 0; g < 2; ++g) {
                const float c00 = cv[o][2 * g], c01 = cv[o][2 * g + 1];
                const float c10 = pcv[o][2 * g], c11 = pcv[o][2 * g + 1];
                const float x00 = xv[o][2 * g], x01 = xv[o][2 * g + 1];
                const float x10 = pxv[o][2 * g], x11 = pxv[o][2 * g + 1];
                float bc = c00, bx = x00;
                if (c01 > bc) { bc = c01; bx = x01; }
                if (c10 > bc) { bc = c10; bx = x10; }
                if (c11 > bc) { bc = c11; bx = x11; }
                bcg[g] = bc * 0.25f; bxg[g] = bx;
            }
            const size_t ho = (size_t)o * NB * np1 + (size_t)b * np1 + (size_t)hy * Wh + hx0;
            *(float2*)(HPc + ho) = make_float2(bcg[0], bcg[1]);
            *(float2*)(HPx + ho) = make_float2(bxg[0], bxg[1]);
        }
    }
}

// ================= enc_h1 = L5+L6+pool fused at H1 =================
// L6 out tile 64x16; s0 72x24 (stride 76, halo 4); s1 68x20 (stride 68, halo 2)
constexpr int BTW = 64, BTH = 16;
constexpr int BSW = 72, BSH = 24, BSS = 76;
constexpr int BAW = 68, BAH = 20, BAS = 68;

__global__ __launch_bounds__(256)
void enc_h1_kernel(const float* __restrict__ xin, const float* __restrict__ cin,   // HP
                   const float* __restrict__ w2, const float* __restrict__ b2,
                   const float* __restrict__ w3, const float* __restrict__ b3,
                   float* __restrict__ HAx, float* __restrict__ HAc,   // x2_ds out (H1)
                   float* __restrict__ QPx, float* __restrict__ QPc,   // pooled (H2)
                   int H, int W) {
    __shared__ __align__(16) float s0c[2][BSH][BSS], s0p[2][BSH][BSS];   // 29184 B
    __shared__ __align__(16) float s1c[2][BAH][BAS], s1p[2][BAH][BAS];   // 21760 B
    __shared__ float sinvf[4], sbf[4];

    int bxi, byi, b; swz_bid(bxi, byi, b);
    const int tid = threadIdx.x;
    const int Y0 = byi * BTH, X0 = bxi * BTW;
    const int npix = H * W;
    const size_t bofs = (size_t)b * npix;
    const size_t chs = (size_t)NB * npix;

    const bool interior = (X0 >= 4) && (X0 + BTW + 4 <= W) && (Y0 >= 4) && (Y0 + BTH + 4 <= H);

    if (tid < 4) {
        const int L = tid >> 1, o = tid & 1;
        const float* wl = (L == 0) ? w2 : w3;
        const float* bl = (L == 0) ? b2 : b3;
        float s = 0.f;
        for (int i = 0; i < 50; ++i) s += wl[o * 50 + i];
        sinvf[tid] = 1.f / s;
        sbf[tid] = bl[o];
    }

    // stage 72x24 x 2ch (halo 4); X0-4 is 16B-aligned when interior
    for (int ci = 0; ci < 2; ++ci) {
        const size_t base = (size_t)ci * chs + bofs;
        if (interior) {
            const size_t o0 = base + (size_t)(Y0 - 4) * W + (X0 - 4);
            for (int i = tid; i < BSH * (BSW / 4); i += 256) {      // 432
                const int ly = i / (BSW / 4), k = i - ly * (BSW / 4);
                const size_t o = o0 + (size_t)ly * W + 4 * k;
                const float4 cv = *(const float4*)(cin + o);
                const float4 xv = *(const float4*)(xin + o);
                *(float4*)&s0c[ci][ly][4 * k] = cv;
                *(float4*)&s0p[ci][ly][4 * k] = make_float4(xv.x * cv.x, xv.y * cv.y,
                                                            xv.z * cv.z, xv.w * cv.w);
            }
        } else {
            for (int i = tid; i < BSH * BSW; i += 256) {
                const int ly = i / BSW, lx = i - ly * BSW;
                const int gy = Y0 + ly - 4, gx = X0 + lx - 4;
                float cv = 0.f, pv = 0.f;
                if (gy >= 0 && gy < H && gx >= 0 && gx < W) {
                    const size_t o = base + (size_t)gy * W + gx;
                    cv = cin[o]; pv = xin[o] * cv;
                }
                s0c[ci][ly][lx] = cv; s0p[ci][ly][lx] = pv;
            }
        }
    }
    __syncthreads();

    // L5 (w2): 68x20 -> s1
    for (int u = tid; u < BAH * (BAW / 4); u += 256) {     // 340 units
        const int row = u / (BAW / 4), lx4 = (u - row * (BAW / 4)) * 4;
        f32x2 ca[4], pa[4];
        conv5x4<2>(&s0c[0][row][lx4], &s0p[0][row][lx4], BSH * BSS, BSS, w2, ca, pa);
        const f32x2 iv = { sinvf[0], sinvf[1] };
        const f32x2 bb = { sbf[0], sbf[1] };
        float cq[2][4], pq[2][4];
        if (interior) {
#pragma unroll
            for (int j = 0; j < 4; ++j) {
                f32x2 r = { frcp(ca[j].x + 1e-20f), frcp(ca[j].y + 1e-20f) };
                const f32x2 xv = pa[j] * r + bb;
                const f32x2 cvv = ca[j] * iv;
                cq[0][j] = cvv.x;            cq[1][j] = cvv.y;
                pq[0][j] = xv.x * cvv.x;     pq[1][j] = xv.y * cvv.y;
            }
        } else {
            const int gy = Y0 + row - 2;
#pragma unroll
            for (int j = 0; j < 4; ++j) {
                const int gx = X0 + lx4 + j - 2;
                const bool in = (gy >= 0 && gy < H && gx >= 0 && gx < W);
                f32x2 r = { frcp(ca[j].x + 1e-20f), frcp(ca[j].y + 1e-20f) };
                const f32x2 xv = pa[j] * r + bb;
                const f32x2 cvv = ca[j] * iv;
                cq[0][j] = in ? cvv.x : 0.f;            cq[1][j] = in ? cvv.y : 0.f;
                pq[0][j] = in ? xv.x * cvv.x : 0.f;     pq[1][j] = in ? xv.y * cvv.y : 0.f;
            }
        }
#pragma unroll
        for (int o = 0; o < 2; ++o) {
            *(float4*)&s1c[o][row][lx4] = make_float4(cq[o][0], cq[o][1], cq[o][2], cq[o][3]);
            *(float4*)&s1p[o][row][lx4] = make_float4(pq[o][0], pq[o][1], pq[o][2], pq[o][3]);
        }
    }
    __syncthreads();

    // L6 (w3) + pool: 64x16, all 256 threads (exact tiling at H1)
    {
        const int row = tid >> 4, lx4 = (tid & 15) * 4;
        f32x2 ca[4], pa[4];
        conv5x4<2>(&s1c[0][row][lx4], &s1p[0][row][lx4], BAH * BAS, BAS, w3, ca, pa);
        float xv[2][4], cv[2][4];
#pragma unroll
        for (int j = 0; j < 4; ++j) {
            f32x2 r = { frcp(ca[j].x + 1e-20f), frcp(ca[j].y + 1e-20f) };
            xv[0][j] = pa[j].x * r.x + sbf[2];  xv[1][j] = pa[j].y * r.y + sbf[3];
            cv[0][j] = ca[j].x * sinvf[2];      cv[1][j] = ca[j].y * sinvf[3];
        }
        const int gy = Y0 + row, gx = X0 + lx4;
        const size_t base = bofs + (size_t)gy * W + gx;
#pragma unroll
        for (int o = 0; o < 2; ++o) {
            *(float4*)(HAx + o * chs + base) = make_float4(xv[o][0], xv[o][1], xv[o][2], xv[o][3]);
            *(float4*)(HAc + o * chs + base) = make_float4(cv[o][0], cv[o][1], cv[o][2], cv[o][3]);
        }
        float pcv[2][4], pxv[2][4];
#pragma unroll
        for (int o = 0; o < 2; ++o)
#pragma unroll
            for (int j = 0; j < 4; ++j) {
                pcv[o][j] = __shfl_xor(cv[o][j], 16);
                pxv[o][j] = __shfl_xor(xv[o][j], 16);
            }
        if ((row & 1) == 0) {
            const int Wh = W >> 1;
            const int np1 = (H >> 1) * Wh;
            const int hy = gy >> 1;
            const int hx0 = gx >> 1;
#pragma unroll
            for (int o = 0; o < 2; ++o) {
                float bcg[2], bxg[2];
#pragma unroll
                for (int g = 0; g < 2; ++g) {
                    const float c00 = cv[o][2 * g], c01 = cv[o][2 * g + 1];
                    const float c10 = pcv[o][2 * g], c11 = pcv[o][2 * g + 1];
                    const float x00 = xv[o][2 * g], x01 = xv[o][2 * g + 1];
                    const float x10 = pxv[o][2 * g], x11 = pxv[o][2 * g + 1];
                    float bc = c00, bx = x00;
                    if (c01 > bc) { bc = c01; bx = x01; }
                    if (c10 > bc) { bc = c10; bx = x10; }
                    if (c11 > bc) { bc = c11; bx = x11; }
                    bcg[g] = bc * 0.25f; bxg[g] = bx;
                }
                const size_t ho = (size_t)o * NB * np1 + (size_t)b * np1 + (size_t)hy * Wh + hx0;
                *(float2*)(QPc + ho) = make_float2(bcg[0], bcg[1]);
                *(float2*)(QPx + ho) = make_float2(bxg[0], bxg[1]);
            }
        }
    }
}

// ================= navg5v: 5x5 conv only (4 px/thread) =================
__global__ __launch_bounds__(256)
void navg5v_kernel(const float* __restrict__ xin, const float* __restrict__ cin,
                   const float* __restrict__ w, const float* __restrict__ bias,
                   float* __restrict__ xout, float* __restrict__ cout,
                   int H, int W) {
    __shared__ __align__(16) float sc[2][VSH][VSW], sp[2][VSH][VSW];
    __shared__ float sinvf[2];

    int bxi, byi, b; swz_bid(bxi, byi, b);
    const int tid = threadIdx.x;
    const int Y0 = byi * VTH, X0 = bxi * VTW;
    const int npix = H * W;
    const size_t bofs = (size_t)b * npix;
    const size_t chs = (size_t)NB * npix;

    const bool interior = (X0 >= 2) && (X0 + VTW + 2 <= W) && (Y0 >= 2) && (Y0 + VTH + 2 <= H);

    if (tid < 2) {
        float s = 0.f;
        for (int i = 0; i < 50; ++i) s += w[tid * 50 + i];
        sinvf[tid] = 1.f / s;
    }
    stage5(xin, cin, sc, sp, tid, Y0, X0, H, W, bofs, chs, interior);
    __syncthreads();

    const int row = tid >> 4, lx4 = (tid & 15) * 4;
    f32x2 ca[4], pa[4];
    conv5x4<2>(&sc[0][row][lx4], &sp[0][row][lx4], VSH * VSW, VSW, w, ca, pa);

    const int gy = Y0 + row, gx = X0 + lx4;
    if (gy < H && gx < W) {
        const float bb0 = bias[0], bb1 = bias[1];
        float xq[2][4], cq[2][4];
#pragma unroll
        for (int j = 0; j < 4; ++j) {
            f32x2 r = { frcp(ca[j].x + 1e-20f), frcp(ca[j].y + 1e-20f) };
            xq[0][j] = pa[j].x * r.x + bb0;  xq[1][j] = pa[j].y * r.y + bb1;
            cq[0][j] = ca[j].x * sinvf[0];   cq[1][j] = ca[j].y * sinvf[1];
        }
        const size_t off = bofs + (size_t)gy * W + gx;
#pragma unroll
        for (int o = 0; o < 2; ++o) {
            *(float4*)(xout + o * chs + off) = make_float4(xq[o][0], xq[o][1], xq[o][2], xq[o][3]);
            *(float4*)(cout + o * chs + off) = make_float4(cq[o][0], cq[o][1], cq[o][2], cq[o][3]);
        }
    }
}

// ================= sub-res 3x3 cat kernel (1 px/thread, small grids) ======
template<bool UPA, bool UPB>
__global__ __launch_bounds__(256)
void navg3_kernel(const float* __restrict__ xA, const float* __restrict__ cA,
                  const float* __restrict__ xB, const float* __restrict__ cB,
                  const float* __restrict__ w, const float* __restrict__ bias,
                  float* __restrict__ xout, float* __restrict__ cout,
                  int H, int W) {
    __shared__ float sc[4][TY + 2][TX + 2];
    __shared__ float sp[4][TY + 2][TX + 2];
    __shared__ float sinvf[2];

    const int b = blockIdx.z;
    const int npix = H * W;
    const size_t chs = (size_t)NB * npix;
    const int tid = threadIdx.y * TX + threadIdx.x;

    if (tid < 2) {
        float s = 0.f;
        for (int i = 0; i < 36; ++i) s += w[tid * 36 + i];
        sinvf[tid] = 1.f / s;
    }

    const int y0 = blockIdx.y * TY - 1;
    const int x0 = blockIdx.x * TX - 1;
    const int Ws2 = W >> 1;
    const int npixS = (H >> 1) * Ws2;

#pragma unroll
    for (int ch = 0; ch < 4; ++ch) {
        const bool up = (ch < 2) ? UPA : UPB;
        const float* xs = (ch < 2) ? xA : xB;
        const float* cs = (ch < 2) ? cA : cB;
        const int sch = ch & 1;
        const size_t base = up ? ((size_t)sch * NB * npixS + (size_t)b * npixS)
                               : ((size_t)sch * chs + (size_t)b * npix);
        for (int i = tid; i < (TY + 2) * (TX + 2); i += 256) {
            const int ly = i / (TX + 2), lx = i % (TX + 2);
            const int gy = y0 + ly, gx = x0 + lx;
            float cv = 0.f, pv = 0.f;
            if (gy >= 0 && gy < H && gx >= 0 && gx < W) {
                const size_t o = up ? (base + (size_t)(gy >> 1) * Ws2 + (gx >> 1))
                                    : (base + (size_t)gy * W + gx);
                cv = cs[o];
                pv = xs[o] * cv;
            }
            sc[ch][ly][lx] = cv;
            sp[ch][ly][lx] = pv;
        }
    }
    __syncthreads();

    const int gh = blockIdx.y * TY + threadIdx.y;
    const int gw = blockIdx.x * TX + threadIdx.x;
    if (gh < H && gw < W) {
        const size_t off = (size_t)b * npix + (size_t)gh * W + gw;
        f32x2 ca = splat2(0.f), pa = splat2(0.f);
#pragma unroll
        for (int ci = 0; ci < 4; ++ci)
#pragma unroll
            for (int kh = 0; kh < 3; ++kh)
#pragma unroll
                for (int kw = 0; kw < 3; ++kw) {
                    const int q = (ci * 3 + kh) * 3 + kw;
                    const f32x2 wv = { w[q], w[36 + q] };
                    ca += splat2(sc[ci][threadIdx.y + kh][threadIdx.x + kw]) * wv;
                    pa += splat2(sp[ci][threadIdx.y + kh][threadIdx.x + kw]) * wv;
                }
        xout[off]       = pa.x * frcp(ca.x + 1e-20f) + bias[0];
        xout[chs + off] = pa.y * frcp(ca.y + 1e-20f) + bias[1];
        cout[off]       = ca.x * sinvf[0];
        cout[chs + off] = ca.y * sinvf[1];
    }
}

// ========== vectorized 3x3 cat (4 px/thread, tile 32x32) ==========
constexpr int GTW = 32, GTH = 32, GSW = 34, GSH = 34, GSS = 36;

template<bool UPA, bool UPB>
__device__ __forceinline__ void stage3(const float* __restrict__ xA, const float* __restrict__ cA,
                                       const float* __restrict__ xB, const float* __restrict__ cB,
                                       float (*sc)[GSH][GSS], float (*sp)[GSH][GSS],
                                       int tid, int Y0, int X0, int H, int W,
                                       int b) {
    const int npix = H * W;
    const size_t chs = (size_t)NB * npix;
    const int Ws2 = W >> 1;
    const int npixS = (H >> 1) * Ws2;
#pragma unroll
    for (int ch = 0; ch < 4; ++ch) {
        const bool up = (ch < 2) ? UPA : UPB;
        const float* xs = (ch < 2) ? xA : xB;
        const float* cs = (ch < 2) ? cA : cB;
        const int sch = ch & 1;
        const size_t base = up ? ((size_t)sch * NB * npixS + (size_t)b * npixS)
                               : ((size_t)sch * chs + (size_t)b * npix);
        for (int i = tid; i < GSH * GSW; i += 256) {
            const int ly = i / GSW, lx = i - ly * GSW;
            const int gy = Y0 + ly - 1, gx = X0 + lx - 1;
            float cv = 0.f, pv = 0.f;
            if (gy >= 0 && gy < H && gx >= 0 && gx < W) {
                const size_t o = up ? (base + (size_t)(gy >> 1) * Ws2 + (gx >> 1))
                                    : (base + (size_t)gy * W + gx);
                cv = cs[o]; pv = xs[o] * cv;
            }
            sc[ch][ly][lx] = cv; sp[ch][ly][lx] = pv;
        }
    }
}

template<bool UPA, bool UPB>
__global__ __launch_bounds__(256)
void navg3v_kernel(const float* __restrict__ xA, const float* __restrict__ cA,
                   const float* __restrict__ xB, const float* __restrict__ cB,
                   const float* __restrict__ w, const float* __restrict__ bias,
                   float* __restrict__ xout, float* __restrict__ cout,
                   int H, int W) {
    __shared__ __align__(16) float sc[4][GSH][GSS], sp[4][GSH][GSS];   // 39168 B
    __shared__ float sinvf[2];

    int bxi, byi, b; swz_bid(bxi, byi, b);
    const int tid = threadIdx.x;
    const int Y0 = byi * GTH, X0 = bxi * GTW;
    const int npix = H * W;
    const size_t bofs = (size_t)b * npix;
    const size_t chs = (size_t)NB * npix;

    if (tid < 2) {
        float s = 0.f;
        for (int i = 0; i < 36; ++i) s += w[tid * 36 + i];
        sinvf[tid] = 1.f / s;
    }
    stage3<UPA, UPB>(xA, cA, xB, cB, sc, sp, tid, Y0, X0, H, W, b);
    __syncthreads();

    const int row = tid >> 3, lx4 = (tid & 7) * 4;
    f32x2 ca[4], pa[4];
    conv3x4<4>(&sc[0][row][lx4], &sp[0][row][lx4], GSH * GSS, GSS, w, ca, pa);

    const int gy = Y0 + row, gx = X0 + lx4;
    if (gy < H && gx < W) {
        const float bb0 = bias[0], bb1 = bias[1];
        float xq[2][4], cq[2][4];
#pragma unroll
        for (int j = 0; j < 4; ++j) {
            xq[0][j] = pa[j].x * frcp(ca[j].x + 1e-20f) + bb0;
            xq[1][j] = pa[j].y * frcp(ca[j].y + 1e-20f) + bb1;
            cq[0][j] = ca[j].x * sinvf[0];
            cq[1][j] = ca[j].y * sinvf[1];
        }
        const size_t off = bofs + (size_t)gy * W + gx;
#pragma unroll
        for (int o = 0; o < 2; ++o) {
            *(float4*)(xout + o * chs + off) = make_float4(xq[o][0], xq[o][1], xq[o][2], xq[o][3]);
            *(float4*)(cout + o * chs + off) = make_float4(cq[o][0], cq[o][1], cq[o][2], cq[o][3]);
        }
    }
}

// ===== final fused layer: cat(up2(A), B) -> 3x3 -> 1x1 =====
__global__ __launch_bounds__(256)
void navg3f_kernel(const float* __restrict__ xA, const float* __restrict__ cA,
                   const float* __restrict__ xB, const float* __restrict__ cB,
                   const float* __restrict__ w, const float* __restrict__ bias,
                   const float* __restrict__ w4, const float* __restrict__ b4,
                   float* __restrict__ xout, float* __restrict__ cout,
                   int H, int W) {
    __shared__ __align__(16) float sc[4][GSH][GSS], sp[4][GSH][GSS];
    __shared__ float sinvf[2];

    int bxi, byi, b; swz_bid(bxi, byi, b);
    const int tid = threadIdx.x;
    const int Y0 = byi * GTH, X0 = bxi * GTW;
    const int npix = H * W;
    const size_t bofs = (size_t)b * npix;

    if (tid < 2) {
        float s = 0.f;
        for (int i = 0; i < 36; ++i) s += w[tid * 36 + i];
        sinvf[tid] = 1.f / s;
    }
    stage3<true, false>(xA, cA, xB, cB, sc, sp, tid, Y0, X0, H, W, b);
    __syncthreads();

    const int row = tid >> 3, lx4 = (tid & 7) * 4;
    f32x2 ca[4], pa[4];
    conv3x4<4>(&sc[0][row][lx4], &sp[0][row][lx4], GSH * GSS, GSS, w, ca, pa);

    const float w40 = w4[0], w41 = w4[1], b40 = b4[0];
    const float inv4 = frcp(w40 + w41);
    const float bb0 = bias[0], bb1 = bias[1];
    float xq[4], cq[4];
#pragma unroll
    for (int j = 0; j < 4; ++j) {
        const float xv0 = pa[j].x * frcp(ca[j].x + 1e-20f) + bb0;
        const float xv1 = pa[j].y * frcp(ca[j].y + 1e-20f) + bb1;
        const float cv0 = ca[j].x * sinvf[0];
        const float cv1 = ca[j].y * sinvf[1];
        const float ca4 = w40 * cv0 + w41 * cv1;
        xq[j] = (w40 * xv0 * cv0 + w41 * xv1 * cv1) * frcp(ca4 + 1e-20f) + b40;
        cq[j] = ca4 * inv4;
    }
    const size_t off = bofs + (size_t)(Y0 + row) * W + (X0 + lx4);
    *(float4*)(xout + off) = make_float4(xq[0], xq[1], xq[2], xq[3]);
    *(float4*)(cout + off) = make_float4(cq[0], cq[1], cq[2], cq[3]);
}

// ================= FALLBACK: fused full-res encoder =================
constexpr int FTW = 32, FTH = 16;
constexpr int FSW = 44, FSH = 28;
constexpr int FAW = 40, FAH = 24;
constexpr int FAS = 44;
constexpr int FBW = 36, FBH = 20;

union EncSmem {
    struct { float c[FSH][FSW]; float p[FSH][FSW]; } s0;
    struct { float c[2][FBH][FBW]; float p[2][FBH][FBW]; } s2;
};

__global__ __launch_bounds__(256)
void enc_full_kernel(const float* __restrict__ x0, const float* __restrict__ c0,
                     const float* __restrict__ w1, const float* __restrict__ b1,
                     const float* __restrict__ w2, const float* __restrict__ b2,
                     const float* __restrict__ w3, const float* __restrict__ b3,
                     float* __restrict__ FAx, float* __restrict__ FAc,
                     float* __restrict__ HPx, float* __restrict__ HPc,
                     int H, int W) {
    __shared__ __align__(16) EncSmem u;
    __shared__ __align__(16) float s1c[2][FAH][FAS], s1p[2][FAH][FAS];
    __shared__ float sinvf[6], sbf[6];

    const int tid = threadIdx.x;
    const int b = blockIdx.z;
    const int Y0 = blockIdx.y * FTH, X0 = blockIdx.x * FTW;
    const int npix = H * W;
    const size_t bofs = (size_t)b * npix;
    const size_t chs = (size_t)NB * npix;

    const bool interior = (X0 >= 6) && (X0 + FTW + 6 <= W) && (Y0 >= 6) && (Y0 + FTH + 6 <= H);

    if (tid < 6) {
        const int L = tid >> 1, o = tid & 1;
        const float* wl = (L == 0) ? w1 : (L == 1) ? w2 : w3;
        const float* bl = (L == 0) ? b1 : (L == 1) ? b2 : b3;
        const int n = (L == 0) ? 25 : 50;
        float s = 0.f;
        for (int i = 0; i < n; ++i) s += wl[o * n + i];
        sinvf[tid] = 1.f / s;
        sbf[tid] = bl[o];
    }

    if (interior) {
        const size_t o0 = bofs + (size_t)(Y0 - 6) * W + (X0 - 6);
        for (int i = tid; i < FSH * FSW; i += 256) {
            const int ly = i / FSW, lx = i - ly * FSW;
            const size_t o = o0 + (size_t)ly * W + lx;
            const float cv = c0[o];
            u.s0.c[ly][lx] = cv; u.s0.p[ly][lx] = x0[o] * cv;
        }
    } else {
        for (int i = tid; i < FSH * FSW; i += 256) {
            const int ly = i / FSW, lx = i - ly * FSW;
            const int gy = Y0 + ly - 6, gx = X0 + lx - 6;
            float cv = 0.f, pv = 0.f;
            if (gy >= 0 && gy < H && gx >= 0 && gx < W) {
                const size_t o = bofs + (size_t)gy * W + gx;
                cv = c0[o]; pv = x0[o] * cv;
            }
            u.s0.c[ly][lx] = cv; u.s0.p[ly][lx] = pv;
        }
    }
    __syncthreads();

    if (tid < FAH * (FAW / 4)) {
        const int row = tid / (FAW / 4), lx = (tid % (FAW / 4)) * 4;
        f32x2 ca[4], pa[4];
        conv5x4<1>(&u.s0.c[row][lx], &u.s0.p[row][lx], 0, FSW, w1, ca, pa);
        const f32x2 iv = { sinvf[0], sinvf[1] };
        const f32x2 bb = { sbf[0], sbf[1] };
        float cq[2][4], pq[2][4];
        if (interior) {
#pragma unroll
            for (int j = 0; j < 4; ++j) {
                f32x2 r = { frcp(ca[j].x + 1e-20f), frcp(ca[j].y + 1e-20f) };
                const f32x2 xv = pa[j] * r + bb;
                const f32x2 cvv = ca[j] * iv;
                cq[0][j] = cvv.x;            cq[1][j] = cvv.y;
                pq[0][j] = xv.x * cvv.x;     pq[1][j] = xv.y * cvv.y;
            }
        } else {
            const int gy = Y0 + row - 4;
#pragma unroll
            for (int j = 0; j < 4; ++j) {
                const int gx = X0 + lx + j - 4;
                const bool in = (gy >= 0 && gy < H && gx >= 0 && gx < W);
                f32x2 r = { frcp(ca[j].x + 1e-20f), frcp(ca[j].y + 1e-20f) };
                const f32x2 xv = pa[j] * r + bb;
                const f32x2 cvv = ca[j] * iv;
                cq[0][j] = in ? cvv.x : 0.f;            cq[1][j] = in ? cvv.y : 0.f;
                pq[0][j] = in ? xv.x * cvv.x : 0.f;     pq[1][j] = in ? xv.y * cvv.y : 0.f;
            }
        }
#pragma unroll
        for (int o = 0; o < 2; ++o) {
            *(float4*)&s1c[o][row][lx] = make_float4(cq[o][0], cq[o][1], cq[o][2], cq[o][3]);
            *(float4*)&s1p[o][row][lx] = make_float4(pq[o][0], pq[o][1], pq[o][2], pq[o][3]);
        }
    }
    __syncthreads();

    if (tid < FBH * (FBW / 4)) {
        const int row = tid / (FBW / 4), lx = (tid % (FBW / 4)) * 4;
        f32x2 ca[4], pa[4];
        conv5x4<2>(&s1c[0][row][lx], &s1p[0][row][lx], FAH * FAS, FAS, w2, ca, pa);
        const f32x2 iv = { sinvf[2], sinvf[3] };
        const f32x2 bb = { sbf[2], sbf[3] };
        float cq[2][4], pq[2][4];
        if (interior) {
#pragma unroll
            for (int j = 0; j < 4; ++j) {
                f32x2 r = { frcp(ca[j].x + 1e-20f), frcp(ca[j].y + 1e-20f) };
                const f32x2 xv = pa[j] * r + bb;
                const f32x2 cvv = ca[j] * iv;
                cq[0][j] = cvv.x;            cq[1][j] = cvv.y;
                pq[0][j] = xv.x * cvv.x;     pq[1][j] = xv.y * cvv.y;
            }
        } else {
            const int gy = Y0 + row - 2;
#pragma unroll
            for (int j = 0; j < 4; ++j) {
                const int gx = X0 + lx + j - 2;
                const bool in = (gy >= 0 && gy < H && gx >= 0 && gx < W);
                f32x2 r = { frcp(ca[j].x + 1e-20f), frcp(ca[j].y + 1e-20f) };
                const f32x2 xv = pa[j] * r + bb;
                const f32x2 cvv = ca[j] * iv;
                cq[0][j] = in ? cvv.x : 0.f;            cq[1][j] = in ? cvv.y : 0.f;
                pq[0][j] = in ? xv.x * cvv.x : 0.f;     pq[1][j] = in ? xv.y * cvv.y : 0.f;
            }
        }
#pragma unroll
        for (int o = 0; o < 2; ++o) {
            *(float4*)&u.s2.c[o][row][lx] = make_float4(cq[o][0], cq[o][1], cq[o][2], cq[o][3]);
            *(float4*)&u.s2.p[o][row][lx] = make_float4(pq[o][0], pq[o][1], pq[o][2], pq[o][3]);
        }
    }
    __syncthreads();

    if (tid < FTH * (FTW / 4)) {
        const int row = tid / (FTW / 4), lx = (tid % (FTW / 4)) * 4;
        f32x2 ca[4], pa[4];
        conv5x4<2>(&u.s2.c[0][row][lx], &u.s2.p[0][row][lx], FBH * FBW, FBW, w3, ca, pa);
        const f32x2 iv = { sinvf[4], sinvf[5] };
        const f32x2 bb = { sbf[4], sbf[5] };
        float xv[2][4], cv[2][4];
#pragma unroll
        for (int j = 0; j < 4; ++j) {
            f32x2 r = { frcp(ca[j].x + 1e-20f), frcp(ca[j].y + 1e-20f) };
            const f32x2 x2 = pa[j] * r + bb;
            const f32x2 c2 = ca[j] * iv;
            xv[0][j] = x2.x; xv[1][j] = x2.y;
            cv[0][j] = c2.x; cv[1][j] = c2.y;
        }
        const int gy = Y0 + row;
        const size_t base = bofs + (size_t)gy * W + (X0 + lx);
#pragma unroll
        for (int o = 0; o < 2; ++o) {
            *(float4*)(FAx + o * chs + base) = make_float4(xv[o][0], xv[o][1], xv[o][2], xv[o][3]);
            *(float4*)(FAc + o * chs + base) = make_float4(cv[o][0], cv[o][1], cv[o][2], cv[o][3]);
        }
        float pcv[2][4], pxv[2][4];
#pragma unroll
        for (int o = 0; o < 2; ++o)
#pragma unroll
            for (int j = 0; j < 4; ++j) {
                pcv[o][j] = __shfl_xor(cv[o][j], 8);
                pxv[o][j] = __shfl_xor(xv[o][j], 8);
            }
        if ((row & 1) == 0) {
            const int Wh = W >> 1;
            const int np1 = (H >> 1) * Wh;
            const int hy = (Y0 + row) >> 1;
            const int hx0 = (X0 + lx) >> 1;
#pragma unroll
            for (int o = 0; o < 2; ++o)
#pragma unroll
                for (int g = 0; g < 2; ++g) {
                    const float c00 = cv[o][2 * g], c01 = cv[o][2 * g + 1];
                    const float c10 = pcv[o][2 * g], c11 = pcv[o][2 * g + 1];
                    const float x00 = xv[o][2 * g], x01 = xv[o][2 * g + 1];
                    const float x10 = pxv[o][2 * g], x11 = pxv[o][2 * g + 1];
                    float bc = c00, bx = x00;
                    if (c01 > bc) { bc = c01; bx = x01; }
                    if (c10 > bc) { bc = c10; bx = x10; }
                    if (c11 > bc) { bc = c11; bx = x11; }
                    const size_t ho = (size_t)o * NB * np1 + (size_t)b * np1 + (size_t)hy * Wh + hx0 + g;
                    HPc[ho] = bc * 0.25f;
                    HPx[ho] = bx;
                }
        }
    }
}

extern "C" void kernel_launch(void* const* d_in, const int* in_sizes, int n_in,
                              void* d_out, int out_size, void* d_ws, size_t ws_size,
                              hipStream_t stream) {
    const float* x0  = (const float*)d_in[0];
    const float* c0  = (const float*)d_in[1];
    const float* w1  = (const float*)d_in[2];
    const float* w2  = (const float*)d_in[3];
    const float* w3  = (const float*)d_in[4];
    const float* w4  = (const float*)d_in[5];
    const float* w34 = (const float*)d_in[6];
    const float* w23 = (const float*)d_in[7];
    const float* w12 = (const float*)d_in[8];
    const float* b1  = (const float*)d_in[9];
    const float* b2  = (const float*)d_in[10];
    const float* b3  = (const float*)d_in[11];
    const float* b4  = (const float*)d_in[12];
    const float* b34 = (const float*)d_in[13];
    const float* b23 = (const float*)d_in[14];
    const float* b12 = (const float*)d_in[15];

    float* out = (float*)d_out;   // fp32: xout plane then cout plane

    const int H0 = 512, W0 = 640, H1 = 256, W1 = 320, H2 = 128, W2 = 160, H3 = 64, W3 = 80;
    const size_t n0 = (size_t)NB * H0 * W0;
    const size_t n1 = n0 / 4, n2 = n0 / 16, n3 = n0 / 64;

    const size_t arena = 8 * n1 + 8 * n2 + 8 * n3;
    const bool split_enc = ws_size >= (8 * n0 + arena) * sizeof(float);

    float* ws = (float*)d_ws;
    float* FAx = ws;            // x1 (2ch) -- persists to the end
    float* FAc = ws + 2 * n0;   // c1 (2ch)
    float* L2x = nullptr;
    float* L2c = nullptr;
    float* sub;
    if (split_enc) {
        L2x = ws + 4 * n0;
        L2c = ws + 6 * n0;
        sub = ws + 8 * n0;
    } else {
        sub = ws + 4 * n0;
    }
    float* HPx = sub;               sub += 2 * n1;
    float* HPc = sub;               sub += 2 * n1;
    float* HAx = sub;               sub += 2 * n1;
    float* HAc = sub;               sub += 2 * n1;
    float* QPx = sub;               sub += 2 * n2;
    float* QPc = sub;               sub += 2 * n2;
    float* QAx = sub;               sub += 2 * n2;
    float* QAc = sub;               sub += 2 * n2;
    float* EPx = sub;               sub += 2 * n3;
    float* EPc = sub;               sub += 2 * n3;
    float* EAx = sub;               sub += 2 * n3;
    float* EAc = sub;               sub += 2 * n3;

    dim3 blk(TX, TY);
    auto gdim  = [](int W, int H) { return dim3((W + TX - 1) / TX, (H + TY - 1) / TY, NB); };
    auto gdim5 = [](int W, int H) { return dim3((W + VTW - 1) / VTW, (H + VTH - 1) / VTH, NB); };
    auto gdim3v = [](int W, int H) { return dim3((W + GTW - 1) / GTW, (H + GTH - 1) / GTH, NB); };

    if (split_enc) {
        enc12_kernel<<<dim3(W0 / ATW, H0 / ATH, NB), 256, 0, stream>>>(
            x0, c0, w1, b1, w2, b2, L2x, L2c, H0, W0);
        navg5p_kernel<<<gdim5(W0, H0), 256, 0, stream>>>(
            L2x, L2c, w3, b3, FAx, FAc, HPx, HPc, H0, W0);
    } else {
        enc_full_kernel<<<dim3(W0 / FTW, H0 / FTH, NB), 256, 0, stream>>>(
            x0, c0, w1, b1, w2, b2, w3, b3, FAx, FAc, HPx, HPc, H0, W0);
    }

    // L5+L6+pool fused: HP -> HA (x2_ds, H1) + QP (pooled, H2)
    enc_h1_kernel<<<dim3(W1 / BTW, H1 / BTH, NB), 256, 0, stream>>>(
        HPx, HPc, w2, b2, w3, b3, HAx, HAc, QPx, QPc, H1, W1);
    // L8 + pool fused: QP -> QA (x3_ds) + EP (pooled eighth)
    navg5p_kernel<<<gdim5(W2, H2), 256, 0, stream>>>(QPx, QPc, w2, b2, QAx, QAc, EPx, EPc, H2, W2);
    // L10: EP -> EA (w2,b2)  [EA := x4_ds,c4_ds]
    navg5v_kernel<<<gdim5(W3, H3), 256, 0, stream>>>(EPx, EPc, w2, b2, EAx, EAc, H3, W3);
    // L12: cat(QA, up2(EA)) -> QP (w34,b34)
    navg3_kernel<false, true><<<gdim(W2, H2), blk, 0, stream>>>(
        QAx, QAc, EAx, EAc, w34, b34, QPx, QPc, H2, W2);
    // L14: cat(HA=x2_ds, up2(QP)) -> HP (w23,b23)  [vectorized]
    navg3v_kernel<false, true><<<gdim3v(W1, H1), 256, 0, stream>>>(
        HAx, HAc, QPx, QPc, w23, b23, HPx, HPc, H1, W1);
    // L16 + L17 fused: cat(up2(HP), FA) -> full res, then 1x1 w4, fp32 out
    navg3f_kernel<<<gdim3v(W0, H0), 256, 0, stream>>>(
        HPx, HPc, FAx, FAc, w12, b12, w4, b4, out, out + n0, H0, W0);
}